// Round 5
// baseline (280.358 us; speedup 1.0000x reference)
//
#include <hip/hip_runtime.h>
#include <cstdint>
#include <cstddef>

typedef unsigned short u16;
typedef __bf16 bf16_t;
typedef bf16_t bf16x8 __attribute__((ext_vector_type(8)));
typedef float f32x4 __attribute__((ext_vector_type(4)));
typedef float f32x16 __attribute__((ext_vector_type(16)));

__device__ __forceinline__ u16 f32_to_bf16(float f) {
  uint32_t u = __builtin_bit_cast(uint32_t, f);
  u += 0x7fffu + ((u >> 16) & 1u);   // RNE
  return (u16)(u >> 16);
}

// pack two f32 -> two bf16 in one u32 (round-half-up + v_perm_b32); low word = lo
__device__ __forceinline__ uint32_t pack_bf16x2(float lo, float hi) {
  uint32_t a = __builtin_bit_cast(uint32_t, hi) + 0x8000u;
  uint32_t b = __builtin_bit_cast(uint32_t, lo) + 0x8000u;
  return __builtin_amdgcn_perm(a, b, 0x07060302u);
}

// async global->LDS, 16B per lane. LDS dest is wave-uniform base; HW adds lane*16.
__device__ __forceinline__ void gload_lds16(const void* g, void* l) {
  __builtin_amdgcn_global_load_lds(
      (const __attribute__((address_space(1))) unsigned int*)g,
      (__attribute__((address_space(3))) unsigned int*)l, 16, 0, 0);
}

// ---------------- fp32 -> bf16 elementwise convert ----------------
__global__ void cvt_bf16(const float* __restrict__ in, u16* __restrict__ out, int n) {
  int i = (blockIdx.x * 256 + threadIdx.x) * 4;
  if (i < n) {
    float4 f = *(const float4*)(in + i);
    ushort4 o;
    o.x = f32_to_bf16(f.x); o.y = f32_to_bf16(f.y);
    o.z = f32_to_bf16(f.z); o.w = f32_to_bf16(f.w);
    *(ushort4*)(out + i) = o;
  }
}

// ---------------- fp32 [R][C] -> bf16 [C][R] transpose-convert ----------------
__global__ void tconv(const float* __restrict__ in, u16* __restrict__ out, int R, int C) {
  __shared__ u16 t[64][80];
  int tid = threadIdx.x;
  int cb = blockIdx.x * 64, rb = blockIdx.y * 64;
  int rr = tid >> 2, cg = (tid & 3) * 16;
  const float* ip = in + (size_t)(rb + rr) * C + cb + cg;
#pragma unroll
  for (int i = 0; i < 16; ++i) t[rr][cg + i] = f32_to_bf16(ip[i]);
  __syncthreads();
  int cc = tid >> 2, rg = (tid & 3) * 16;
  u16* op = out + (size_t)(cb + cc) * R + rb + rg;
  union { uint4 v[2]; u16 s[16]; } tmp;
#pragma unroll
  for (int i = 0; i < 16; ++i) tmp.s[i] = t[rg + i][cc];
  *(uint4*)op = tmp.v[0];
  *(uint4*)(op + 8) = tmp.v[1];
}

// ---------------- V slice of qkv (bf16) -> Vt' [bh][d=64][t=2048] ----------------
// t is PERMUTED within each 16-group: storage pos p holds t = {0-3,8-11,4-7,12-15}[p].
// This makes the PV MFMA's A-side k-order match the S^T C-register order, so the
// P fragment is built by 16 packs in register order — no cross-lane ops (see attn).
__global__ void vtrans(const u16* __restrict__ qkvb, u16* __restrict__ vt) {
  __shared__ u16 t[64][80];
  int tid = threadIdx.x;
  int bh = blockIdx.x, tb = blockIdx.y * 64;
  int b = bh >> 4, h = bh & 15;
  int tt = tid >> 2, dg = (tid & 3) * 16;
  const u16* ip = qkvb + (size_t)(b * 2048 + tb + tt) * 3072 + 2048 + h * 64 + dg;
  union { uint4 v; u16 s[8]; } a0, a1;
  a0.v = *(const uint4*)ip;
  a1.v = *(const uint4*)(ip + 8);
#pragma unroll
  for (int i = 0; i < 8; ++i) { t[tt][dg + i] = a0.s[i]; t[tt][dg + 8 + i] = a1.s[i]; }
  __syncthreads();
  int dd = tid >> 2, tg = (tid & 3) * 16;
  u16* op = vt + (size_t)(bh * 64 + dd) * 2048 + tb + tg;
  union { uint4 v[2]; u16 s[16]; } tmp;
#pragma unroll
  for (int i = 0; i < 16; ++i) {
    int pi = (i & 3) | ((i & 4) << 1) | ((i & 8) >> 1);  // {0-3,8-11,4-7,12-15}
    tmp.s[i] = t[tg + pi][dd];
  }
  *(uint4*)op = tmp.v[0];
  *(uint4*)(op + 8) = tmp.v[1];
}

// ---------------- 256x256 8-phase bf16 GEMM: C[M,N] = A[M,K]*Bt[N,K]^T + bias --
template <int OUT_BF16>
__global__ __launch_bounds__(512, 2) void gemm256(const u16* __restrict__ A,
                                                  const u16* __restrict__ Bt,
                                                  const float* __restrict__ bias,
                                                  void* __restrict__ Cout,
                                                  int M, int N, int K) {
  __shared__ __align__(16) u16 lds[2][2][16384];  // [buf][0=A,1=B][256*64]
  const int tid = threadIdx.x;
  const int w = tid >> 6, L = tid & 63;
  const int quad = L >> 4, lc = L & 15;
  const int wr = w >> 2, wc = w & 3;          // 2 M-waves x 4 N-waves
  const int wrM = wr * 128, wcN = wc * 64;
  const int rL = L >> 3;                       // row within a wave's 8-row chunk
  const int gsw = (L & 7) ^ rL;                // pre-swizzled source granule

  // XCD-aware bijective block swizzle (gridDim.x % 8 == 0 for both launches)
  const int nbx = N >> 8;
  const int cpx = gridDim.x >> 3;
  const int id = blockIdx.x;
  const int swz = (id & 7) * cpx + (id >> 3);
  const int tileN = (swz % nbx) << 8;
  const int tileM = (swz / nbx) << 8;
  const int nkt = K >> 6;

  u16* const A0 = &lds[0][0][0];
  u16* const B0 = &lds[0][1][0];
  u16* const A1 = &lds[1][0][0];
  u16* const B1 = &lds[1][1][0];

  // stage one 64-row quarter (8 rows per wave, 16B per lane, linear LDS dest)
  auto stageQ = [&](const u16* Mp, int gRow, int kt, u16* reg) {
    int ktc = kt < nkt ? kt : nkt - 1;  // clamped tail: region-safe, count-safe
    const u16* src = Mp + (size_t)(gRow + w * 8 + rL) * K + (ktc << 6) + gsw * 8;
    gload_lds16(src, reg + w * 512);
  };

  f32x4 acc[8][4] = {};
  const int rsw = lc & 7;
  const int g0 = (quad ^ rsw) * 8;        // swizzled ds_read granule, ks=0
  const int g1 = ((4 + quad) ^ rsw) * 8;  // ks=1
  const int aRow = (wrM + lc) * 64;
  const int bRow = (wcN + lc) * 64;

  // ---- prologue: tile0 (8 quarters) + tile1 (6 quarters; B-hi comes at ph1)
  stageQ(A, tileM + 0, 0, A0 + 0);
  stageQ(A, tileM + 128, 0, A0 + 8192);
  stageQ(Bt, tileN + 0, 0, B0 + 0);
  stageQ(Bt, tileN + 64, 0, B0 + 4096);
  stageQ(A, tileM + 64, 0, A0 + 4096);
  stageQ(A, tileM + 192, 0, A0 + 12288);
  stageQ(Bt, tileN + 128, 0, B0 + 8192);
  stageQ(Bt, tileN + 192, 0, B0 + 12288);
  stageQ(A, tileM + 0, 1, A1 + 0);
  stageQ(A, tileM + 128, 1, A1 + 8192);
  stageQ(Bt, tileN + 0, 1, B1 + 0);
  stageQ(Bt, tileN + 64, 1, B1 + 4096);
  stageQ(A, tileM + 64, 1, A1 + 4096);
  stageQ(A, tileM + 192, 1, A1 + 12288);
  asm volatile("s_waitcnt vmcnt(6)" ::: "memory");  // tile0 resident
  __builtin_amdgcn_s_barrier();

  // ---- one 4-phase group: compute K-tile T from (Ab,Bb); prefetch
  //      B-hi(T+1)->Bob at ph1, tile(T+2)->(Ab,Bb) at ph2/3/4.
  auto group = [&](u16* Ab, u16* Bb, u16* Bob, int T) {
    bf16x8 af[4][2], blo[2][2], bhi[2][2];
    // ph1: read A-lo + B-lo; stage B r2,r3 of T+1 (other buf)
#pragma unroll
    for (int mi = 0; mi < 4; ++mi) {
      af[mi][0] = *(const bf16x8*)&Ab[aRow + mi * 1024 + g0];
      af[mi][1] = *(const bf16x8*)&Ab[aRow + mi * 1024 + g1];
    }
#pragma unroll
    for (int ni = 0; ni < 2; ++ni) {
      blo[ni][0] = *(const bf16x8*)&Bb[bRow + ni * 1024 + g0];
      blo[ni][1] = *(const bf16x8*)&Bb[bRow + ni * 1024 + g1];
    }
    stageQ(Bt, tileN + 128, T + 1, Bob + 8192);
    stageQ(Bt, tileN + 192, T + 1, Bob + 12288);
    asm volatile("" ::: "memory");
    __builtin_amdgcn_s_barrier();
    asm volatile("s_waitcnt lgkmcnt(0)" ::: "memory");
    __builtin_amdgcn_s_setprio(1);
#pragma unroll
    for (int mi = 0; mi < 4; ++mi)
#pragma unroll
      for (int ni = 0; ni < 2; ++ni) {
        acc[mi][ni] = __builtin_amdgcn_mfma_f32_16x16x32_bf16(af[mi][0], blo[ni][0], acc[mi][ni], 0, 0, 0);
        acc[mi][ni] = __builtin_amdgcn_mfma_f32_16x16x32_bf16(af[mi][1], blo[ni][1], acc[mi][ni], 0, 0, 0);
      }
    __builtin_amdgcn_s_setprio(0);
    asm volatile("" ::: "memory");
    __builtin_amdgcn_s_barrier();
    // ph2: read B-hi; stage A q0,q2 of T+2 (freed by ph1 reads)
#pragma unroll
    for (int ni = 0; ni < 2; ++ni) {
      bhi[ni][0] = *(const bf16x8*)&Bb[bRow + (2 + ni) * 1024 + g0];
      bhi[ni][1] = *(const bf16x8*)&Bb[bRow + (2 + ni) * 1024 + g1];
    }
    stageQ(A, tileM + 0, T + 2, Ab + 0);
    stageQ(A, tileM + 128, T + 2, Ab + 8192);
    asm volatile("" ::: "memory");
    __builtin_amdgcn_s_barrier();
    asm volatile("s_waitcnt lgkmcnt(0)" ::: "memory");
    __builtin_amdgcn_s_setprio(1);
#pragma unroll
    for (int mi = 0; mi < 4; ++mi)
#pragma unroll
      for (int ni = 0; ni < 2; ++ni) {
        acc[mi][ni + 2] = __builtin_amdgcn_mfma_f32_16x16x32_bf16(af[mi][0], bhi[ni][0], acc[mi][ni + 2], 0, 0, 0);
        acc[mi][ni + 2] = __builtin_amdgcn_mfma_f32_16x16x32_bf16(af[mi][1], bhi[ni][1], acc[mi][ni + 2], 0, 0, 0);
      }
    __builtin_amdgcn_s_setprio(0);
    asm volatile("" ::: "memory");
    __builtin_amdgcn_s_barrier();
    // ph3: read A-hi; stage B r0,r1 of T+2 (freed by ph2 reads)
#pragma unroll
    for (int mi = 0; mi < 4; ++mi) {
      af[mi][0] = *(const bf16x8*)&Ab[aRow + (4 + mi) * 1024 + g0];
      af[mi][1] = *(const bf16x8*)&Ab[aRow + (4 + mi) * 1024 + g1];
    }
    stageQ(Bt, tileN + 0, T + 2, Bb + 0);
    stageQ(Bt, tileN + 64, T + 2, Bb + 4096);
    asm volatile("" ::: "memory");
    __builtin_amdgcn_s_barrier();
    asm volatile("s_waitcnt lgkmcnt(0)" ::: "memory");
    __builtin_amdgcn_s_setprio(1);
#pragma unroll
    for (int mi = 0; mi < 4; ++mi)
#pragma unroll
      for (int ni = 0; ni < 2; ++ni) {
        acc[mi + 4][ni + 2] = __builtin_amdgcn_mfma_f32_16x16x32_bf16(af[mi][0], bhi[ni][0], acc[mi + 4][ni + 2], 0, 0, 0);
        acc[mi + 4][ni + 2] = __builtin_amdgcn_mfma_f32_16x16x32_bf16(af[mi][1], bhi[ni][1], acc[mi + 4][ni + 2], 0, 0, 0);
      }
    __builtin_amdgcn_s_setprio(0);
    asm volatile("" ::: "memory");
    __builtin_amdgcn_s_barrier();
    // ph4: no reads; stage A q1,q3 of T+2 (freed by ph3 reads); counted vmcnt
    stageQ(A, tileM + 64, T + 2, Ab + 4096);
    stageQ(A, tileM + 192, T + 2, Ab + 12288);
    asm volatile("" ::: "memory");
    __builtin_amdgcn_s_barrier();
    __builtin_amdgcn_s_setprio(1);
#pragma unroll
    for (int mi = 0; mi < 4; ++mi)
#pragma unroll
      for (int ni = 0; ni < 2; ++ni) {
        acc[mi + 4][ni] = __builtin_amdgcn_mfma_f32_16x16x32_bf16(af[mi][0], blo[ni][0], acc[mi + 4][ni], 0, 0, 0);
        acc[mi + 4][ni] = __builtin_amdgcn_mfma_f32_16x16x32_bf16(af[mi][1], blo[ni][1], acc[mi + 4][ni], 0, 0, 0);
      }
    __builtin_amdgcn_s_setprio(0);
    asm volatile("s_waitcnt vmcnt(6)" ::: "memory");  // next K-tile resident
    __builtin_amdgcn_s_barrier();
  };

  for (int T = 0; T < nkt; T += 2) {
    group(A0, B0, B1, T);
    group(A1, B1, B0, T + 1);
  }

  // drain in-flight LDS-DMA before this block's LDS can be reassigned
  asm volatile("s_waitcnt vmcnt(0)" ::: "memory");

#pragma unroll
  for (int mi = 0; mi < 8; ++mi) {
    int rowb = tileM + wrM + mi * 16 + quad * 4;
#pragma unroll
    for (int ni = 0; ni < 4; ++ni) {
      int col = tileN + wcN + ni * 16 + lc;
      float bv = bias[col];
#pragma unroll
      for (int r = 0; r < 4; ++r) {
        float v = acc[mi][ni][r] + bv;
        if (OUT_BF16)
          ((u16*)Cout)[(size_t)(rowb + r) * N + col] = f32_to_bf16(v);
        else
          ((float*)Cout)[(size_t)(rowb + r) * N + col] = v;
      }
    }
  }
}

// ---------------- causal flash attention, 32x32 in-register softmax ----------
// 2 waves/block, 32 q-rows per wave (QBLK=64), KVBLK=64. UNPAIRED grid:
// one q-tile per block, grid (64 bh, 32 qt), qt = 31 - blockIdx.y so the
// longest blocks dispatch first (tail absorbed by 8 blocks/CU average).
// SINGLE-buffered K/V LDS (16 KB) -> 10 blocks/CU LDS limit; occupancy is
// the lever (round-4 showed 17% occupancy = dependency-stall-bound; depth-1
// prefetch at low occupancy was null in round 2, so trade it for residency).
// S^T = K·Q^T via mfma_32x32x16: lane owns ONE q column; softmax fully
// in-register (fixed-max exp2, diag mask per-reg, per-lane lsum).
// PV: O^T = V^T·P with consistent k-permutation (vtrans stores t-perm
// {0-3,8-11,4-7,12-15}) -> P built by 16 pack_bf16x2, no cross-lane, no P-LDS.
__global__ __launch_bounds__(128, 4) void attn(const u16* __restrict__ qkvb,
                                               const u16* __restrict__ vt,
                                               u16* __restrict__ yb) {
  __shared__ __align__(16) u16 kv[16][512];  // [0-7:K(t2*4+ds) 8-15:V(d2*4+ks)][lane*8]
  const int tid = threadIdx.x;
  const int w = tid >> 6, L = tid & 63;
  const int l5 = L & 31, hi = L >> 5;
  const int bh = blockIdx.x;
  const int b = bh >> 4, h = bh & 15;
  const int qt = 31 - blockIdx.y;         // longest q-tiles dispatch first
  const float e_c = 0.18033688f;          // (1/sqrt(64)) * log2(e)

  // per-lane staging bases: wave 0 stages the 8 K frags, wave 1 the 8 V frags.
  // K frag (t2,ds): row tk = kb + t2*32 + l5, col d = ds*16 + hi*8 (16B)
  // V frag (d2,ks): row d = d2*32 + l5, col t = kb + ks*16 + hi*8 (16B, permuted t)
  const bool isK = (w == 0);
  const u16* kbase = qkvb + ((size_t)(b * 2048 + l5) * 3072 + 1024 + h * 64 + hi * 8);
  const u16* vbase = vt + ((size_t)(bh * 64 + l5) * 2048 + hi * 8);

  auto stage = [&](int kb2) {
    if (isK) {
#pragma unroll
      for (int i = 0; i < 8; ++i)
        gload_lds16(kbase + (size_t)(kb2 + (i >> 2) * 32) * 3072 + (i & 3) * 16,
                    &kv[i][0]);
    } else {
#pragma unroll
      for (int i = 0; i < 8; ++i)
        gload_lds16(vbase + (size_t)((i >> 2) * 32) * 2048 + kb2 + (i & 3) * 16,
                    &kv[8 + i][0]);
    }
  };

  const int qbase = qt * 64;
  const int qrow = qbase + w * 32 + l5;   // this lane's q row (one column of S^T)
  const int lim = w * 32 + l5 - hi * 4;   // diag keep: 32*t2 + br <= lim

  bf16x8 qf[4];
  {
    const u16* qp = qkvb + ((size_t)(b * 2048 + qrow) * 3072 + h * 64 + hi * 8);
#pragma unroll
    for (int ds = 0; ds < 4; ++ds) qf[ds] = *(const bf16x8*)(qp + ds * 16);
  }
  f32x16 o0 = {}, o1 = {};
  float lsum = 0.f;

  for (int kb = 0; kb <= qbase; kb += 64) {
    const bool diag = (kb == qbase);
    stage(kb);
    __syncthreads();  // own DMA drained (vmcnt 0) + barrier => K and V resident

    // S^T: rows kb..kb+31 -> st0, kb+32..kb+63 -> st1
    f32x16 st0 = {}, st1 = {};
    __builtin_amdgcn_s_setprio(1);
#pragma unroll
    for (int ds = 0; ds < 4; ++ds) {
      bf16x8 k0 = *(const bf16x8*)&kv[ds][L * 8];
      bf16x8 k1 = *(const bf16x8*)&kv[4 + ds][L * 8];
      st0 = __builtin_amdgcn_mfma_f32_32x32x16_bf16(k0, qf[ds], st0, 0, 0, 0);
      st1 = __builtin_amdgcn_mfma_f32_32x32x16_bf16(k1, qf[ds], st1, 0, 0, 0);
    }
    __builtin_amdgcn_s_setprio(0);

    // softmax: p = exp2(s * e_c); mask diag; per-lane lsum
#pragma unroll
    for (int r = 0; r < 16; ++r) {
      float p0 = __builtin_amdgcn_exp2f(st0[r] * e_c);
      float p1 = __builtin_amdgcn_exp2f(st1[r] * e_c);
      if (diag) {
        const int br = (r & 3) + 8 * (r >> 2);
        p0 = (br <= lim) ? p0 : 0.f;
        p1 = (32 + br <= lim) ? p1 : 0.f;
      }
      st0[r] = p0;
      st1[r] = p1;
      lsum += p0 + p1;
    }

    // O^T += V^T · P  (k-permuted slices; pf words = regs in order)
    __builtin_amdgcn_s_setprio(1);
#pragma unroll
    for (int sg = 0; sg < 2; ++sg) {
      union { uint32_t u[4]; bf16x8 v; } pf0, pf1;
#pragma unroll
      for (int q2 = 0; q2 < 4; ++q2) {
        pf0.u[q2] = pack_bf16x2(st0[sg * 8 + q2 * 2], st0[sg * 8 + q2 * 2 + 1]);
        pf1.u[q2] = pack_bf16x2(st1[sg * 8 + q2 * 2], st1[sg * 8 + q2 * 2 + 1]);
      }
      const int ks0 = sg, ks1 = 2 + sg;  // slices of t2=0 / t2=1
      bf16x8 va = *(const bf16x8*)&kv[8 + ks0][L * 8];    // d2=0
      bf16x8 vb = *(const bf16x8*)&kv[12 + ks0][L * 8];   // d2=1
      o0 = __builtin_amdgcn_mfma_f32_32x32x16_bf16(va, pf0.v, o0, 0, 0, 0);
      o1 = __builtin_amdgcn_mfma_f32_32x32x16_bf16(vb, pf0.v, o1, 0, 0, 0);
      va = *(const bf16x8*)&kv[8 + ks1][L * 8];
      vb = *(const bf16x8*)&kv[12 + ks1][L * 8];
      o0 = __builtin_amdgcn_mfma_f32_32x32x16_bf16(va, pf1.v, o0, 0, 0, 0);
      o1 = __builtin_amdgcn_mfma_f32_32x32x16_bf16(vb, pf1.v, o1, 0, 0, 0);
    }
    __builtin_amdgcn_s_setprio(0);

    __syncthreads();  // all waves done reading kv before next stage overwrites
  }

  // column sum: this lane has half the rows of column q; partner (hi^1) the rest
  lsum += __shfl_xor(lsum, 32);
  float inv = 1.f / lsum;

  // store y[qrow][h*64 + d]; lane's d = 32*d2 + 8*g + 4*hi + (0..3)
  u16* yp = yb + (size_t)(b * 2048 + qrow) * 1024 + h * 64 + hi * 4;
#pragma unroll
  for (int g = 0; g < 4; ++g) {
    uint2 pk;
    pk.x = pack_bf16x2(o0[g * 4 + 0] * inv, o0[g * 4 + 1] * inv);
    pk.y = pack_bf16x2(o0[g * 4 + 2] * inv, o0[g * 4 + 3] * inv);
    *(uint2*)(yp + g * 8) = pk;
    pk.x = pack_bf16x2(o1[g * 4 + 0] * inv, o1[g * 4 + 1] * inv);
    pk.y = pack_bf16x2(o1[g * 4 + 2] * inv, o1[g * 4 + 3] * inv);
    *(uint2*)(yp + 32 + g * 8) = pk;
  }
}

extern "C" void kernel_launch(void* const* d_in, const int* in_sizes, int n_in,
                              void* d_out, int out_size, void* d_ws, size_t ws_size,
                              hipStream_t stream) {
  const float* x = (const float*)d_in[0];
  const float* w_attn = (const float*)d_in[1];
  const float* b_attn = (const float*)d_in[2];
  const float* w_proj = (const float*)d_in[3];
  const float* b_proj = (const float*)d_in[4];
  float* out = (float*)d_out;

  char* ws = (char*)d_ws;
  u16* xb = (u16*)ws;    ws += (size_t)8192 * 1024 * 2;
  u16* waT = (u16*)ws;   ws += (size_t)3072 * 1024 * 2;
  u16* wpT = (u16*)ws;   ws += (size_t)1024 * 1024 * 2;
  u16* qkvb = (u16*)ws;  ws += (size_t)8192 * 3072 * 2;
  u16* vtb = (u16*)ws;   ws += (size_t)64 * 64 * 2048 * 2;
  u16* yb = (u16*)ws;    ws += (size_t)8192 * 1024 * 2;

  cvt_bf16<<<8192, 256, 0, stream>>>(x, xb, 8192 * 1024);
  tconv<<<dim3(3072 / 64, 1024 / 64), 256, 0, stream>>>(w_attn, waT, 1024, 3072);
  tconv<<<dim3(1024 / 64, 1024 / 64), 256, 0, stream>>>(w_proj, wpT, 1024, 1024);
  // 256^2 tiles: QKV grid = (8192/256)*(3072/256) = 384 blocks (384%8==0)
  gemm256<1><<<dim3(384), 512, 0, stream>>>(xb, waT, b_attn, qkvb, 8192, 3072, 1024);
  vtrans<<<dim3(64, 32), 256, 0, stream>>>(qkvb, vtb);
  attn<<<dim3(64, 32), 128, 0, stream>>>(qkvb, vtb, yb);
  // proj grid = (8192/256)*(1024/256) = 128 blocks (128%8==0)
  gemm256<0><<<dim3(128), 512, 0, stream>>>(yb, wpT, b_proj, out, 8192, 1024, 1024);
}

// Round 6
// 257.984 us; speedup vs baseline: 1.0867x; 1.0867x over previous
//
#include <hip/hip_runtime.h>
#include <cstdint>
#include <cstddef>

typedef unsigned short u16;
typedef __bf16 bf16_t;
typedef bf16_t bf16x8 __attribute__((ext_vector_type(8)));
typedef float f32x4 __attribute__((ext_vector_type(4)));
typedef float f32x16 __attribute__((ext_vector_type(16)));

__device__ __forceinline__ u16 f32_to_bf16(float f) {
  uint32_t u = __builtin_bit_cast(uint32_t, f);
  u += 0x7fffu + ((u >> 16) & 1u);   // RNE
  return (u16)(u >> 16);
}

// pack two f32 -> two bf16 in one u32 (round-half-up + v_perm_b32); low word = lo
__device__ __forceinline__ uint32_t pack_bf16x2(float lo, float hi) {
  uint32_t a = __builtin_bit_cast(uint32_t, hi) + 0x8000u;
  uint32_t b = __builtin_bit_cast(uint32_t, lo) + 0x8000u;
  return __builtin_amdgcn_perm(a, b, 0x07060302u);
}

// async global->LDS, 16B per lane. LDS dest is wave-uniform base; HW adds lane*16.
__device__ __forceinline__ void gload_lds16(const void* g, void* l) {
  __builtin_amdgcn_global_load_lds(
      (const __attribute__((address_space(1))) unsigned int*)g,
      (__attribute__((address_space(3))) unsigned int*)l, 16, 0, 0);
}

// ---------------- fp32 -> bf16 elementwise convert ----------------
__global__ void cvt_bf16(const float* __restrict__ in, u16* __restrict__ out, int n) {
  int i = (blockIdx.x * 256 + threadIdx.x) * 4;
  if (i < n) {
    float4 f = *(const float4*)(in + i);
    ushort4 o;
    o.x = f32_to_bf16(f.x); o.y = f32_to_bf16(f.y);
    o.z = f32_to_bf16(f.z); o.w = f32_to_bf16(f.w);
    *(ushort4*)(out + i) = o;
  }
}

// ---------------- fp32 [R][C] -> bf16 [C][R] transpose-convert ----------------
__global__ void tconv(const float* __restrict__ in, u16* __restrict__ out, int R, int C) {
  __shared__ u16 t[64][80];
  int tid = threadIdx.x;
  int cb = blockIdx.x * 64, rb = blockIdx.y * 64;
  int rr = tid >> 2, cg = (tid & 3) * 16;
  const float* ip = in + (size_t)(rb + rr) * C + cb + cg;
#pragma unroll
  for (int i = 0; i < 16; ++i) t[rr][cg + i] = f32_to_bf16(ip[i]);
  __syncthreads();
  int cc = tid >> 2, rg = (tid & 3) * 16;
  u16* op = out + (size_t)(cb + cc) * R + rb + rg;
  union { uint4 v[2]; u16 s[16]; } tmp;
#pragma unroll
  for (int i = 0; i < 16; ++i) tmp.s[i] = t[rg + i][cc];
  *(uint4*)op = tmp.v[0];
  *(uint4*)(op + 8) = tmp.v[1];
}

// ---------------- V slice of qkv (bf16) -> Vt' [bh][d=64][t=2048] ----------------
// t is PERMUTED within each 16-group: storage pos p holds t = {0-3,8-11,4-7,12-15}[p].
// This makes the PV MFMA's A-side k-order match the S^T C-register order, so the
// P fragment is built by 16 packs in register order — no cross-lane ops (see attn).
__global__ void vtrans(const u16* __restrict__ qkvb, u16* __restrict__ vt) {
  __shared__ u16 t[64][80];
  int tid = threadIdx.x;
  int bh = blockIdx.x, tb = blockIdx.y * 64;
  int b = bh >> 4, h = bh & 15;
  int tt = tid >> 2, dg = (tid & 3) * 16;
  const u16* ip = qkvb + (size_t)(b * 2048 + tb + tt) * 3072 + 2048 + h * 64 + dg;
  union { uint4 v; u16 s[8]; } a0, a1;
  a0.v = *(const uint4*)ip;
  a1.v = *(const uint4*)(ip + 8);
#pragma unroll
  for (int i = 0; i < 8; ++i) { t[tt][dg + i] = a0.s[i]; t[tt][dg + 8 + i] = a1.s[i]; }
  __syncthreads();
  int dd = tid >> 2, tg = (tid & 3) * 16;
  u16* op = vt + (size_t)(bh * 64 + dd) * 2048 + tb + tg;
  union { uint4 v[2]; u16 s[16]; } tmp;
#pragma unroll
  for (int i = 0; i < 16; ++i) {
    int pi = (i & 3) | ((i & 4) << 1) | ((i & 8) >> 1);  // {0-3,8-11,4-7,12-15}
    tmp.s[i] = t[tg + pi][dd];
  }
  *(uint4*)op = tmp.v[0];
  *(uint4*)(op + 8) = tmp.v[1];
}

// ---------------- 256x256 8-phase bf16 GEMM: C[M,N] = A[M,K]*Bt[N,K]^T + bias --
template <int OUT_BF16>
__global__ __launch_bounds__(512, 2) void gemm256(const u16* __restrict__ A,
                                                  const u16* __restrict__ Bt,
                                                  const float* __restrict__ bias,
                                                  void* __restrict__ Cout,
                                                  int M, int N, int K) {
  __shared__ __align__(16) u16 lds[2][2][16384];  // [buf][0=A,1=B][256*64]
  const int tid = threadIdx.x;
  const int w = tid >> 6, L = tid & 63;
  const int quad = L >> 4, lc = L & 15;
  const int wr = w >> 2, wc = w & 3;          // 2 M-waves x 4 N-waves
  const int wrM = wr * 128, wcN = wc * 64;
  const int rL = L >> 3;                       // row within a wave's 8-row chunk
  const int gsw = (L & 7) ^ rL;                // pre-swizzled source granule

  // XCD-aware bijective block swizzle (gridDim.x % 8 == 0 for both launches)
  const int nbx = N >> 8;
  const int cpx = gridDim.x >> 3;
  const int id = blockIdx.x;
  const int swz = (id & 7) * cpx + (id >> 3);
  const int tileN = (swz % nbx) << 8;
  const int tileM = (swz / nbx) << 8;
  const int nkt = K >> 6;

  u16* const A0 = &lds[0][0][0];
  u16* const B0 = &lds[0][1][0];
  u16* const A1 = &lds[1][0][0];
  u16* const B1 = &lds[1][1][0];

  // stage one 64-row quarter (8 rows per wave, 16B per lane, linear LDS dest)
  auto stageQ = [&](const u16* Mp, int gRow, int kt, u16* reg) {
    int ktc = kt < nkt ? kt : nkt - 1;  // clamped tail: region-safe, count-safe
    const u16* src = Mp + (size_t)(gRow + w * 8 + rL) * K + (ktc << 6) + gsw * 8;
    gload_lds16(src, reg + w * 512);
  };

  f32x4 acc[8][4] = {};
  const int rsw = lc & 7;
  const int g0 = (quad ^ rsw) * 8;        // swizzled ds_read granule, ks=0
  const int g1 = ((4 + quad) ^ rsw) * 8;  // ks=1
  const int aRow = (wrM + lc) * 64;
  const int bRow = (wcN + lc) * 64;

  // ---- prologue: tile0 (8 quarters) + tile1 (6 quarters; B-hi comes at ph1)
  stageQ(A, tileM + 0, 0, A0 + 0);
  stageQ(A, tileM + 128, 0, A0 + 8192);
  stageQ(Bt, tileN + 0, 0, B0 + 0);
  stageQ(Bt, tileN + 64, 0, B0 + 4096);
  stageQ(A, tileM + 64, 0, A0 + 4096);
  stageQ(A, tileM + 192, 0, A0 + 12288);
  stageQ(Bt, tileN + 128, 0, B0 + 8192);
  stageQ(Bt, tileN + 192, 0, B0 + 12288);
  stageQ(A, tileM + 0, 1, A1 + 0);
  stageQ(A, tileM + 128, 1, A1 + 8192);
  stageQ(Bt, tileN + 0, 1, B1 + 0);
  stageQ(Bt, tileN + 64, 1, B1 + 4096);
  stageQ(A, tileM + 64, 1, A1 + 4096);
  stageQ(A, tileM + 192, 1, A1 + 12288);
  asm volatile("s_waitcnt vmcnt(6)" ::: "memory");  // tile0 resident
  __builtin_amdgcn_s_barrier();

  // ---- one 4-phase group: compute K-tile T from (Ab,Bb); prefetch
  //      B-hi(T+1)->Bob at ph1, tile(T+2)->(Ab,Bb) at ph2/3/4.
  auto group = [&](u16* Ab, u16* Bb, u16* Bob, int T) {
    bf16x8 af[4][2], blo[2][2], bhi[2][2];
    // ph1: read A-lo + B-lo; stage B r2,r3 of T+1 (other buf)
#pragma unroll
    for (int mi = 0; mi < 4; ++mi) {
      af[mi][0] = *(const bf16x8*)&Ab[aRow + mi * 1024 + g0];
      af[mi][1] = *(const bf16x8*)&Ab[aRow + mi * 1024 + g1];
    }
#pragma unroll
    for (int ni = 0; ni < 2; ++ni) {
      blo[ni][0] = *(const bf16x8*)&Bb[bRow + ni * 1024 + g0];
      blo[ni][1] = *(const bf16x8*)&Bb[bRow + ni * 1024 + g1];
    }
    stageQ(Bt, tileN + 128, T + 1, Bob + 8192);
    stageQ(Bt, tileN + 192, T + 1, Bob + 12288);
    asm volatile("" ::: "memory");
    __builtin_amdgcn_s_barrier();
    asm volatile("s_waitcnt lgkmcnt(0)" ::: "memory");
    __builtin_amdgcn_s_setprio(1);
#pragma unroll
    for (int mi = 0; mi < 4; ++mi)
#pragma unroll
      for (int ni = 0; ni < 2; ++ni) {
        acc[mi][ni] = __builtin_amdgcn_mfma_f32_16x16x32_bf16(af[mi][0], blo[ni][0], acc[mi][ni], 0, 0, 0);
        acc[mi][ni] = __builtin_amdgcn_mfma_f32_16x16x32_bf16(af[mi][1], blo[ni][1], acc[mi][ni], 0, 0, 0);
      }
    __builtin_amdgcn_s_setprio(0);
    asm volatile("" ::: "memory");
    __builtin_amdgcn_s_barrier();
    // ph2: read B-hi; stage A q0,q2 of T+2 (freed by ph1 reads)
#pragma unroll
    for (int ni = 0; ni < 2; ++ni) {
      bhi[ni][0] = *(const bf16x8*)&Bb[bRow + (2 + ni) * 1024 + g0];
      bhi[ni][1] = *(const bf16x8*)&Bb[bRow + (2 + ni) * 1024 + g1];
    }
    stageQ(A, tileM + 0, T + 2, Ab + 0);
    stageQ(A, tileM + 128, T + 2, Ab + 8192);
    asm volatile("" ::: "memory");
    __builtin_amdgcn_s_barrier();
    asm volatile("s_waitcnt lgkmcnt(0)" ::: "memory");
    __builtin_amdgcn_s_setprio(1);
#pragma unroll
    for (int mi = 0; mi < 4; ++mi)
#pragma unroll
      for (int ni = 0; ni < 2; ++ni) {
        acc[mi][ni + 2] = __builtin_amdgcn_mfma_f32_16x16x32_bf16(af[mi][0], bhi[ni][0], acc[mi][ni + 2], 0, 0, 0);
        acc[mi][ni + 2] = __builtin_amdgcn_mfma_f32_16x16x32_bf16(af[mi][1], bhi[ni][1], acc[mi][ni + 2], 0, 0, 0);
      }
    __builtin_amdgcn_s_setprio(0);
    asm volatile("" ::: "memory");
    __builtin_amdgcn_s_barrier();
    // ph3: read A-hi; stage B r0,r1 of T+2 (freed by ph2 reads)
#pragma unroll
    for (int mi = 0; mi < 4; ++mi) {
      af[mi][0] = *(const bf16x8*)&Ab[aRow + (4 + mi) * 1024 + g0];
      af[mi][1] = *(const bf16x8*)&Ab[aRow + (4 + mi) * 1024 + g1];
    }
    stageQ(Bt, tileN + 0, T + 2, Bb + 0);
    stageQ(Bt, tileN + 64, T + 2, Bb + 4096);
    asm volatile("" ::: "memory");
    __builtin_amdgcn_s_barrier();
    asm volatile("s_waitcnt lgkmcnt(0)" ::: "memory");
    __builtin_amdgcn_s_setprio(1);
#pragma unroll
    for (int mi = 0; mi < 4; ++mi)
#pragma unroll
      for (int ni = 0; ni < 2; ++ni) {
        acc[mi + 4][ni + 2] = __builtin_amdgcn_mfma_f32_16x16x32_bf16(af[mi][0], bhi[ni][0], acc[mi + 4][ni + 2], 0, 0, 0);
        acc[mi + 4][ni + 2] = __builtin_amdgcn_mfma_f32_16x16x32_bf16(af[mi][1], bhi[ni][1], acc[mi + 4][ni + 2], 0, 0, 0);
      }
    __builtin_amdgcn_s_setprio(0);
    asm volatile("" ::: "memory");
    __builtin_amdgcn_s_barrier();
    // ph4: no reads; stage A q1,q3 of T+2 (freed by ph3 reads); counted vmcnt
    stageQ(A, tileM + 64, T + 2, Ab + 4096);
    stageQ(A, tileM + 192, T + 2, Ab + 12288);
    asm volatile("" ::: "memory");
    __builtin_amdgcn_s_barrier();
    __builtin_amdgcn_s_setprio(1);
#pragma unroll
    for (int mi = 0; mi < 4; ++mi)
#pragma unroll
      for (int ni = 0; ni < 2; ++ni) {
        acc[mi + 4][ni] = __builtin_amdgcn_mfma_f32_16x16x32_bf16(af[mi][0], blo[ni][0], acc[mi + 4][ni], 0, 0, 0);
        acc[mi + 4][ni] = __builtin_amdgcn_mfma_f32_16x16x32_bf16(af[mi][1], blo[ni][1], acc[mi + 4][ni], 0, 0, 0);
      }
    __builtin_amdgcn_s_setprio(0);
    asm volatile("s_waitcnt vmcnt(6)" ::: "memory");  // next K-tile resident
    __builtin_amdgcn_s_barrier();
  };

  for (int T = 0; T < nkt; T += 2) {
    group(A0, B0, B1, T);
    group(A1, B1, B0, T + 1);
  }

  // drain in-flight LDS-DMA before this block's LDS can be reassigned
  asm volatile("s_waitcnt vmcnt(0)" ::: "memory");

#pragma unroll
  for (int mi = 0; mi < 8; ++mi) {
    int rowb = tileM + wrM + mi * 16 + quad * 4;
#pragma unroll
    for (int ni = 0; ni < 4; ++ni) {
      int col = tileN + wcN + ni * 16 + lc;
      float bv = bias[col];
#pragma unroll
      for (int r = 0; r < 4; ++r) {
        float v = acc[mi][ni][r] + bv;
        if (OUT_BF16)
          ((u16*)Cout)[(size_t)(rowb + r) * N + col] = f32_to_bf16(v);
        else
          ((float*)Cout)[(size_t)(rowb + r) * N + col] = v;
      }
    }
  }
}

// ---------------- causal flash attention, 8-wave 32x32 in-register softmax ----
// QBLK=256: 8 waves/block, wave w owns q rows [qbase+32w, +32); KVBLK=64.
// Grid (64 bh, 8) = 512 blocks = EXACTLY 2/CU, all co-resident, zero tail.
// qt = (y<4) ? 7-y : y-4 -> the two blocks sharing a CU sum to 36 tiles
// (balanced makespan). Same-bh blocks land on one XCD (64%8==0) -> K/V L2 hits.
// Each staged 16 KB K/V tile feeds 8 waves (4x the round-5 amortization);
// staging split 2 DMA/wave. Double-buffered LDS (32 KB), depth-1 prefetch,
// ONE __syncthreads per tile (its vmcnt(0) drains loads issued a full compute
// phase earlier). Causal: waves skip compute (not barriers) for tiles past
// their diagonal; partial tiles masked with lim = wq+l5-4hi-kb (reduces to
// the round-5 diag mask when kb==wq tile). Math identical to round 5
// (exp2(s*e_c), pack_bf16x2, same MFMA order) -> same absmax.
__global__ __launch_bounds__(512, 4) void attn(const u16* __restrict__ qkvb,
                                               const u16* __restrict__ vt,
                                               u16* __restrict__ yb) {
  __shared__ __align__(16) u16 kv[2][16][512];  // [buf][0-7:K(t2*4+ds) 8-15:V(d2*4+ks)][lane*8]
  const int tid = threadIdx.x;
  const int w = tid >> 6, L = tid & 63;
  const int l5 = L & 31, hi = L >> 5;
  const int bh = blockIdx.x;
  const int b = bh >> 4, h = bh & 15;
  const int qt = (blockIdx.y < 4) ? (7 - blockIdx.y) : (blockIdx.y - 4);
  const float e_c = 0.18033688f;          // (1/sqrt(64)) * log2(e)
  const int qbase = qt * 256;
  const int wq = qbase + w * 32;          // wave's first q row
  const int nk = qbase + 256;             // kb upper bound (exclusive)

  // staging: wave w stages fragments {2w, 2w+1}. w<4 -> K frags f=2w (t2=w>>1,
  // ds=(w&1)*2, +1); w>=4 -> V frags g=2(w-4) (d2=(w-4)>>1, ks=((w-4)&1)*2, +1).
  // K frag (t2,ds): lane reads row kb+t2*32+l5, col ds*16+hi*8 (16B).
  // V frag (d2,ks): lane reads row d2*32+l5, col kb+ks*16+hi*8 (16B, permuted t).
  const int u = w - 4;
  const u16* kb0 = qkvb + (size_t)(b * 2048 + (w >> 1) * 32 + l5) * 3072 + 1024 +
                   h * 64 + (w & 1) * 32 + hi * 8;
  const u16* vb0 = vt + (size_t)(bh * 64 + (u >> 1) * 32 + l5) * 2048 +
                   (u & 1) * 32 + hi * 8;

  auto stage = [&](int kb2, int buf) {
    if (w < 4) {
      const u16* s = kb0 + (size_t)kb2 * 3072;
      gload_lds16(s, &kv[buf][2 * w][0]);
      gload_lds16(s + 16, &kv[buf][2 * w + 1][0]);
    } else {
      const u16* s = vb0 + kb2;
      gload_lds16(s, &kv[buf][8 + 2 * u][0]);
      gload_lds16(s + 16, &kv[buf][8 + 2 * u + 1][0]);
    }
  };

  const int qrow = wq + l5;               // this lane's q row (one column of S^T)
  bf16x8 qf[4];
  {
    const u16* qp = qkvb + ((size_t)(b * 2048 + qrow) * 3072 + h * 64 + hi * 8);
#pragma unroll
    for (int ds = 0; ds < 4; ++ds) qf[ds] = *(const bf16x8*)(qp + ds * 16);
  }
  f32x16 o0 = {}, o1 = {};
  float lsum = 0.f;

  int par = 0;
  stage(0, 0);  // prologue: tile0 in flight

  for (int kb = 0; kb < nk; kb += 64) {
    __syncthreads();  // drains DMA issued a full tile ago; kv[par] resident
    stage((kb + 64 < nk) ? kb + 64 : 0, par ^ 1);  // depth-1 prefetch (clamped)

    if (kb <= wq + 31) {  // wave-uniform: this wave has unmasked rows in tile
      const bool part = (kb + 63 > wq);   // some rows need the causal mask
      const int lim = qrow - 4 * hi - kb; // keep: (r&3)+8*(r>>2)+32*t2 <= lim

      // S^T: rows kb..kb+31 -> st0, kb+32..kb+63 -> st1
      f32x16 st0 = {}, st1 = {};
      __builtin_amdgcn_s_setprio(1);
#pragma unroll
      for (int ds = 0; ds < 4; ++ds) {
        bf16x8 k0 = *(const bf16x8*)&kv[par][ds][L * 8];
        bf16x8 k1 = *(const bf16x8*)&kv[par][4 + ds][L * 8];
        st0 = __builtin_amdgcn_mfma_f32_32x32x16_bf16(k0, qf[ds], st0, 0, 0, 0);
        st1 = __builtin_amdgcn_mfma_f32_32x32x16_bf16(k1, qf[ds], st1, 0, 0, 0);
      }
      __builtin_amdgcn_s_setprio(0);

      // softmax: p = exp2(s * e_c); mask partial tiles; per-lane lsum
#pragma unroll
      for (int r = 0; r < 16; ++r) {
        float p0 = __builtin_amdgcn_exp2f(st0[r] * e_c);
        float p1 = __builtin_amdgcn_exp2f(st1[r] * e_c);
        if (part) {
          const int br = (r & 3) + 8 * (r >> 2);
          p0 = (br <= lim) ? p0 : 0.f;
          p1 = (32 + br <= lim) ? p1 : 0.f;
        }
        st0[r] = p0;
        st1[r] = p1;
        lsum += p0 + p1;
      }

      // O^T += V^T · P  (k-permuted slices; pf words = regs in order)
      __builtin_amdgcn_s_setprio(1);
#pragma unroll
      for (int sg = 0; sg < 2; ++sg) {
        union { uint32_t u[4]; bf16x8 v; } pf0, pf1;
#pragma unroll
        for (int q2 = 0; q2 < 4; ++q2) {
          pf0.u[q2] = pack_bf16x2(st0[sg * 8 + q2 * 2], st0[sg * 8 + q2 * 2 + 1]);
          pf1.u[q2] = pack_bf16x2(st1[sg * 8 + q2 * 2], st1[sg * 8 + q2 * 2 + 1]);
        }
        const int ks0 = sg, ks1 = 2 + sg;  // slices of t2=0 / t2=1
        bf16x8 va = *(const bf16x8*)&kv[par][8 + ks0][L * 8];    // d2=0
        bf16x8 vb = *(const bf16x8*)&kv[par][12 + ks0][L * 8];   // d2=1
        o0 = __builtin_amdgcn_mfma_f32_32x32x16_bf16(va, pf0.v, o0, 0, 0, 0);
        o1 = __builtin_amdgcn_mfma_f32_32x32x16_bf16(vb, pf0.v, o1, 0, 0, 0);
        va = *(const bf16x8*)&kv[par][8 + ks1][L * 8];
        vb = *(const bf16x8*)&kv[par][12 + ks1][L * 8];
        o0 = __builtin_amdgcn_mfma_f32_32x32x16_bf16(va, pf1.v, o0, 0, 0, 0);
        o1 = __builtin_amdgcn_mfma_f32_32x32x16_bf16(vb, pf1.v, o1, 0, 0, 0);
      }
      __builtin_amdgcn_s_setprio(0);
    }

    par ^= 1;
  }

  // column sum: this lane has half the rows of column q; partner (hi^1) the rest
  lsum += __shfl_xor(lsum, 32);
  float inv = 1.f / lsum;

  // store y[qrow][h*64 + d]; lane's d = 32*d2 + 8*g + 4*hi + (0..3)
  u16* yp = yb + (size_t)(b * 2048 + qrow) * 1024 + h * 64 + hi * 4;
#pragma unroll
  for (int g = 0; g < 4; ++g) {
    uint2 pk;
    pk.x = pack_bf16x2(o0[g * 4 + 0] * inv, o0[g * 4 + 1] * inv);
    pk.y = pack_bf16x2(o0[g * 4 + 2] * inv, o0[g * 4 + 3] * inv);
    *(uint2*)(yp + g * 8) = pk;
    pk.x = pack_bf16x2(o1[g * 4 + 0] * inv, o1[g * 4 + 1] * inv);
    pk.y = pack_bf16x2(o1[g * 4 + 2] * inv, o1[g * 4 + 3] * inv);
    *(uint2*)(yp + 32 + g * 8) = pk;
  }

  // drain the final dummy prefetch before this block's LDS can be reassigned
  asm volatile("s_waitcnt vmcnt(0)" ::: "memory");
}

extern "C" void kernel_launch(void* const* d_in, const int* in_sizes, int n_in,
                              void* d_out, int out_size, void* d_ws, size_t ws_size,
                              hipStream_t stream) {
  const float* x = (const float*)d_in[0];
  const float* w_attn = (const float*)d_in[1];
  const float* b_attn = (const float*)d_in[2];
  const float* w_proj = (const float*)d_in[3];
  const float* b_proj = (const float*)d_in[4];
  float* out = (float*)d_out;

  char* ws = (char*)d_ws;
  u16* xb = (u16*)ws;    ws += (size_t)8192 * 1024 * 2;
  u16* waT = (u16*)ws;   ws += (size_t)3072 * 1024 * 2;
  u16* wpT = (u16*)ws;   ws += (size_t)1024 * 1024 * 2;
  u16* qkvb = (u16*)ws;  ws += (size_t)8192 * 3072 * 2;
  u16* vtb = (u16*)ws;   ws += (size_t)64 * 64 * 2048 * 2;
  u16* yb = (u16*)ws;    ws += (size_t)8192 * 1024 * 2;

  cvt_bf16<<<8192, 256, 0, stream>>>(x, xb, 8192 * 1024);
  tconv<<<dim3(3072 / 64, 1024 / 64), 256, 0, stream>>>(w_attn, waT, 1024, 3072);
  tconv<<<dim3(1024 / 64, 1024 / 64), 256, 0, stream>>>(w_proj, wpT, 1024, 1024);
  // 256^2 tiles: QKV grid = (8192/256)*(3072/256) = 384 blocks (384%8==0)
  gemm256<1><<<dim3(384), 512, 0, stream>>>(xb, waT, b_attn, qkvb, 8192, 3072, 1024);
  vtrans<<<dim3(64, 32), 256, 0, stream>>>(qkvb, vtb);
  attn<<<dim3(64, 8), 512, 0, stream>>>(qkvb, vtb, yb);
  // proj grid = (8192/256)*(1024/256) = 128 blocks (128%8==0)
  gemm256<0><<<dim3(128), 512, 0, stream>>>(yb, wpT, b_proj, out, 8192, 1024, 1024);
}

// Round 8
// 246.464 us; speedup vs baseline: 1.1375x; 1.0467x over previous
//
#include <hip/hip_runtime.h>
#include <cstdint>
#include <cstddef>

typedef unsigned short u16;
typedef __bf16 bf16_t;
typedef bf16_t bf16x8 __attribute__((ext_vector_type(8)));
typedef float f32x4 __attribute__((ext_vector_type(4)));
typedef float f32x16 __attribute__((ext_vector_type(16)));

__device__ __forceinline__ u16 f32_to_bf16(float f) {
  uint32_t u = __builtin_bit_cast(uint32_t, f);
  u += 0x7fffu + ((u >> 16) & 1u);   // RNE
  return (u16)(u >> 16);
}

// pack two f32 -> two bf16 in one u32 (round-half-up + v_perm_b32); low word = lo
__device__ __forceinline__ uint32_t pack_bf16x2(float lo, float hi) {
  uint32_t a = __builtin_bit_cast(uint32_t, hi) + 0x8000u;
  uint32_t b = __builtin_bit_cast(uint32_t, lo) + 0x8000u;
  return __builtin_amdgcn_perm(a, b, 0x07060302u);
}

// async global->LDS, 16B per lane. LDS dest is wave-uniform base; HW adds lane*16.
__device__ __forceinline__ void gload_lds16(const void* g, void* l) {
  __builtin_amdgcn_global_load_lds(
      (const __attribute__((address_space(1))) unsigned int*)g,
      (__attribute__((address_space(3))) unsigned int*)l, 16, 0, 0);
}

// ---------------- fp32 -> bf16 elementwise convert ----------------
__global__ void cvt_bf16(const float* __restrict__ in, u16* __restrict__ out, int n) {
  int i = (blockIdx.x * 256 + threadIdx.x) * 4;
  if (i < n) {
    float4 f = *(const float4*)(in + i);
    ushort4 o;
    o.x = f32_to_bf16(f.x); o.y = f32_to_bf16(f.y);
    o.z = f32_to_bf16(f.z); o.w = f32_to_bf16(f.w);
    *(ushort4*)(out + i) = o;
  }
}

// ---------------- fp32 [R][C] -> bf16 [C][R] transpose-convert ----------------
__global__ void tconv(const float* __restrict__ in, u16* __restrict__ out, int R, int C) {
  __shared__ u16 t[64][80];
  int tid = threadIdx.x;
  int cb = blockIdx.x * 64, rb = blockIdx.y * 64;
  int rr = tid >> 2, cg = (tid & 3) * 16;
  const float* ip = in + (size_t)(rb + rr) * C + cb + cg;
#pragma unroll
  for (int i = 0; i < 16; ++i) t[rr][cg + i] = f32_to_bf16(ip[i]);
  __syncthreads();
  int cc = tid >> 2, rg = (tid & 3) * 16;
  u16* op = out + (size_t)(cb + cc) * R + rb + rg;
  union { uint4 v[2]; u16 s[16]; } tmp;
#pragma unroll
  for (int i = 0; i < 16; ++i) tmp.s[i] = t[rg + i][cc];
  *(uint4*)op = tmp.v[0];
  *(uint4*)(op + 8) = tmp.v[1];
}

// ---------------- V slice of qkv (bf16) -> Vt' [bh][d=64][t=2048] ----------------
// t is PERMUTED within each 16-group: storage pos p holds t = {0-3,8-11,4-7,12-15}[p].
// This makes the PV MFMA's A-side k-order match the S^T C-register order, so the
// P fragment is built by 16 packs in register order — no cross-lane ops (see attn).
__global__ void vtrans(const u16* __restrict__ qkvb, u16* __restrict__ vt) {
  __shared__ u16 t[64][80];
  int tid = threadIdx.x;
  int bh = blockIdx.x, tb = blockIdx.y * 64;
  int b = bh >> 4, h = bh & 15;
  int tt = tid >> 2, dg = (tid & 3) * 16;
  const u16* ip = qkvb + (size_t)(b * 2048 + tb + tt) * 3072 + 2048 + h * 64 + dg;
  union { uint4 v; u16 s[8]; } a0, a1;
  a0.v = *(const uint4*)ip;
  a1.v = *(const uint4*)(ip + 8);
#pragma unroll
  for (int i = 0; i < 8; ++i) { t[tt][dg + i] = a0.s[i]; t[tt][dg + 8 + i] = a1.s[i]; }
  __syncthreads();
  int dd = tid >> 2, tg = (tid & 3) * 16;
  u16* op = vt + (size_t)(bh * 64 + dd) * 2048 + tb + tg;
  union { uint4 v[2]; u16 s[16]; } tmp;
#pragma unroll
  for (int i = 0; i < 16; ++i) {
    int pi = (i & 3) | ((i & 4) << 1) | ((i & 8) >> 1);  // {0-3,8-11,4-7,12-15}
    tmp.s[i] = t[tg + pi][dd];
  }
  *(uint4*)op = tmp.v[0];
  *(uint4*)(op + 8) = tmp.v[1];
}

// ---------------- 256x256 8-phase bf16 GEMM: C[M,N] = A[M,K]*Bt[N,K]^T + bias --
template <int OUT_BF16>
__global__ __launch_bounds__(512, 2) void gemm256(const u16* __restrict__ A,
                                                  const u16* __restrict__ Bt,
                                                  const float* __restrict__ bias,
                                                  void* __restrict__ Cout,
                                                  int M, int N, int K) {
  __shared__ __align__(16) u16 lds[2][2][16384];  // [buf][0=A,1=B][256*64]
  const int tid = threadIdx.x;
  const int w = tid >> 6, L = tid & 63;
  const int quad = L >> 4, lc = L & 15;
  const int wr = w >> 2, wc = w & 3;          // 2 M-waves x 4 N-waves
  const int wrM = wr * 128, wcN = wc * 64;
  const int rL = L >> 3;                       // row within a wave's 8-row chunk
  const int gsw = (L & 7) ^ rL;                // pre-swizzled source granule

  // XCD-aware bijective block swizzle (gridDim.x % 8 == 0 for both launches)
  const int nbx = N >> 8;
  const int cpx = gridDim.x >> 3;
  const int id = blockIdx.x;
  const int swz = (id & 7) * cpx + (id >> 3);
  const int tileN = (swz % nbx) << 8;
  const int tileM = (swz / nbx) << 8;
  const int nkt = K >> 6;

  u16* const A0 = &lds[0][0][0];
  u16* const B0 = &lds[0][1][0];
  u16* const A1 = &lds[1][0][0];
  u16* const B1 = &lds[1][1][0];

  // stage one 64-row quarter (8 rows per wave, 16B per lane, linear LDS dest)
  auto stageQ = [&](const u16* Mp, int gRow, int kt, u16* reg) {
    int ktc = kt < nkt ? kt : nkt - 1;  // clamped tail: region-safe, count-safe
    const u16* src = Mp + (size_t)(gRow + w * 8 + rL) * K + (ktc << 6) + gsw * 8;
    gload_lds16(src, reg + w * 512);
  };

  f32x4 acc[8][4] = {};
  const int rsw = lc & 7;
  const int g0 = (quad ^ rsw) * 8;        // swizzled ds_read granule, ks=0
  const int g1 = ((4 + quad) ^ rsw) * 8;  // ks=1
  const int aRow = (wrM + lc) * 64;
  const int bRow = (wcN + lc) * 64;

  // ---- prologue: tile0 (8 quarters) + tile1 (6 quarters; B-hi comes at ph1)
  stageQ(A, tileM + 0, 0, A0 + 0);
  stageQ(A, tileM + 128, 0, A0 + 8192);
  stageQ(Bt, tileN + 0, 0, B0 + 0);
  stageQ(Bt, tileN + 64, 0, B0 + 4096);
  stageQ(A, tileM + 64, 0, A0 + 4096);
  stageQ(A, tileM + 192, 0, A0 + 12288);
  stageQ(Bt, tileN + 128, 0, B0 + 8192);
  stageQ(Bt, tileN + 192, 0, B0 + 12288);
  stageQ(A, tileM + 0, 1, A1 + 0);
  stageQ(A, tileM + 128, 1, A1 + 8192);
  stageQ(Bt, tileN + 0, 1, B1 + 0);
  stageQ(Bt, tileN + 64, 1, B1 + 4096);
  stageQ(A, tileM + 64, 1, A1 + 4096);
  stageQ(A, tileM + 192, 1, A1 + 12288);
  asm volatile("s_waitcnt vmcnt(6)" ::: "memory");  // tile0 resident
  __builtin_amdgcn_s_barrier();

  // ---- one 4-phase group: compute K-tile T from (Ab,Bb); prefetch
  //      B-hi(T+1)->Bob at ph1, tile(T+2)->(Ab,Bb) at ph2/3/4.
  auto group = [&](u16* Ab, u16* Bb, u16* Bob, int T) {
    bf16x8 af[4][2], blo[2][2], bhi[2][2];
    // ph1: read A-lo + B-lo; stage B r2,r3 of T+1 (other buf)
#pragma unroll
    for (int mi = 0; mi < 4; ++mi) {
      af[mi][0] = *(const bf16x8*)&Ab[aRow + mi * 1024 + g0];
      af[mi][1] = *(const bf16x8*)&Ab[aRow + mi * 1024 + g1];
    }
#pragma unroll
    for (int ni = 0; ni < 2; ++ni) {
      blo[ni][0] = *(const bf16x8*)&Bb[bRow + ni * 1024 + g0];
      blo[ni][1] = *(const bf16x8*)&Bb[bRow + ni * 1024 + g1];
    }
    stageQ(Bt, tileN + 128, T + 1, Bob + 8192);
    stageQ(Bt, tileN + 192, T + 1, Bob + 12288);
    asm volatile("" ::: "memory");
    __builtin_amdgcn_s_barrier();
    asm volatile("s_waitcnt lgkmcnt(0)" ::: "memory");
    __builtin_amdgcn_s_setprio(1);
#pragma unroll
    for (int mi = 0; mi < 4; ++mi)
#pragma unroll
      for (int ni = 0; ni < 2; ++ni) {
        acc[mi][ni] = __builtin_amdgcn_mfma_f32_16x16x32_bf16(af[mi][0], blo[ni][0], acc[mi][ni], 0, 0, 0);
        acc[mi][ni] = __builtin_amdgcn_mfma_f32_16x16x32_bf16(af[mi][1], blo[ni][1], acc[mi][ni], 0, 0, 0);
      }
    __builtin_amdgcn_s_setprio(0);
    asm volatile("" ::: "memory");
    __builtin_amdgcn_s_barrier();
    // ph2: read B-hi; stage A q0,q2 of T+2 (freed by ph1 reads)
#pragma unroll
    for (int ni = 0; ni < 2; ++ni) {
      bhi[ni][0] = *(const bf16x8*)&Bb[bRow + (2 + ni) * 1024 + g0];
      bhi[ni][1] = *(const bf16x8*)&Bb[bRow + (2 + ni) * 1024 + g1];
    }
    stageQ(A, tileM + 0, T + 2, Ab + 0);
    stageQ(A, tileM + 128, T + 2, Ab + 8192);
    asm volatile("" ::: "memory");
    __builtin_amdgcn_s_barrier();
    asm volatile("s_waitcnt lgkmcnt(0)" ::: "memory");
    __builtin_amdgcn_s_setprio(1);
#pragma unroll
    for (int mi = 0; mi < 4; ++mi)
#pragma unroll
      for (int ni = 0; ni < 2; ++ni) {
        acc[mi][ni + 2] = __builtin_amdgcn_mfma_f32_16x16x32_bf16(af[mi][0], bhi[ni][0], acc[mi][ni + 2], 0, 0, 0);
        acc[mi][ni + 2] = __builtin_amdgcn_mfma_f32_16x16x32_bf16(af[mi][1], bhi[ni][1], acc[mi][ni + 2], 0, 0, 0);
      }
    __builtin_amdgcn_s_setprio(0);
    asm volatile("" ::: "memory");
    __builtin_amdgcn_s_barrier();
    // ph3: read A-hi; stage B r0,r1 of T+2 (freed by ph2 reads)
#pragma unroll
    for (int mi = 0; mi < 4; ++mi) {
      af[mi][0] = *(const bf16x8*)&Ab[aRow + (4 + mi) * 1024 + g0];
      af[mi][1] = *(const bf16x8*)&Ab[aRow + (4 + mi) * 1024 + g1];
    }
    stageQ(Bt, tileN + 0, T + 2, Bb + 0);
    stageQ(Bt, tileN + 64, T + 2, Bb + 4096);
    asm volatile("" ::: "memory");
    __builtin_amdgcn_s_barrier();
    asm volatile("s_waitcnt lgkmcnt(0)" ::: "memory");
    __builtin_amdgcn_s_setprio(1);
#pragma unroll
    for (int mi = 0; mi < 4; ++mi)
#pragma unroll
      for (int ni = 0; ni < 2; ++ni) {
        acc[mi + 4][ni + 2] = __builtin_amdgcn_mfma_f32_16x16x32_bf16(af[mi][0], bhi[ni][0], acc[mi + 4][ni + 2], 0, 0, 0);
        acc[mi + 4][ni + 2] = __builtin_amdgcn_mfma_f32_16x16x32_bf16(af[mi][1], bhi[ni][1], acc[mi + 4][ni + 2], 0, 0, 0);
      }
    __builtin_amdgcn_s_setprio(0);
    asm volatile("" ::: "memory");
    __builtin_amdgcn_s_barrier();
    // ph4: no reads; stage A q1,q3 of T+2 (freed by ph3 reads); counted vmcnt
    stageQ(A, tileM + 64, T + 2, Ab + 4096);
    stageQ(A, tileM + 192, T + 2, Ab + 12288);
    asm volatile("" ::: "memory");
    __builtin_amdgcn_s_barrier();
    __builtin_amdgcn_s_setprio(1);
#pragma unroll
    for (int mi = 0; mi < 4; ++mi)
#pragma unroll
      for (int ni = 0; ni < 2; ++ni) {
        acc[mi + 4][ni] = __builtin_amdgcn_mfma_f32_16x16x32_bf16(af[mi][0], blo[ni][0], acc[mi + 4][ni], 0, 0, 0);
        acc[mi + 4][ni] = __builtin_amdgcn_mfma_f32_16x16x32_bf16(af[mi][1], blo[ni][1], acc[mi + 4][ni], 0, 0, 0);
      }
    __builtin_amdgcn_s_setprio(0);
    asm volatile("s_waitcnt vmcnt(6)" ::: "memory");  // next K-tile resident
    __builtin_amdgcn_s_barrier();
  };

  for (int T = 0; T < nkt; T += 2) {
    group(A0, B0, B1, T);
    group(A1, B1, B0, T + 1);
  }

  // drain in-flight LDS-DMA before this block's LDS can be reassigned
  asm volatile("s_waitcnt vmcnt(0)" ::: "memory");

#pragma unroll
  for (int mi = 0; mi < 8; ++mi) {
    int rowb = tileM + wrM + mi * 16 + quad * 4;
#pragma unroll
    for (int ni = 0; ni < 4; ++ni) {
      int col = tileN + wcN + ni * 16 + lc;
      float bv = bias[col];
#pragma unroll
      for (int r = 0; r < 4; ++r) {
        float v = acc[mi][ni][r] + bv;
        if (OUT_BF16)
          ((u16*)Cout)[(size_t)(rowb + r) * N + col] = f32_to_bf16(v);
        else
          ((float*)Cout)[(size_t)(rowb + r) * N + col] = v;
      }
    }
  }
}

// ---------------- 128x256 8-phase bf16 GEMM (exact-grid variant) ----------------
// Same schedule family as gemm256, re-derived for BM=128: 8 waves as 2M x 4N,
// per-wave output 64x64 (acc[4][4]); LDS 96 KB (A 16K x2buf + B 32K x2buf).
// Quarters: A={q0,q1}, B={r0..r3}. Reads: ph1 A-lo+B-lo, ph2 B-hi, ph3 A-hi.
// Freed-after: B quarters after ph2-end barrier, A quarters after ph3-end.
// Stages: ph1 -> B r2,r3(T+1) into other-B; ph3 -> B r0,r1(T+2) into self-B;
// ph4 -> A q0,q1(T+2) into self-A. 6 stages/group = 1 tile. vmcnt ledger:
// enter group(T) with 4 outstanding (T+1's {r0,r1,q0,q1}); +2+2+2 = 10; end
// vmcnt(4) drains T+1's 6. Prologue issues 10, vmcnt(4) drains tile0's 6.
template <int OUT_BF16>
__global__ __launch_bounds__(512, 2) void gemm128(const u16* __restrict__ A,
                                                  const u16* __restrict__ Bt,
                                                  const float* __restrict__ bias,
                                                  void* __restrict__ Cout,
                                                  int M, int N, int K) {
  __shared__ __align__(16) u16 Abuf[2][8192];    // [buf][128 rows x 64 k]
  __shared__ __align__(16) u16 Bbuf[2][16384];   // [buf][256 rows x 64 k]
  const int tid = threadIdx.x;
  const int w = tid >> 6, L = tid & 63;
  const int quad = L >> 4, lc = L & 15;
  const int wr = w >> 2, wc = w & 3;   // 2 M-waves (64 rows) x 4 N-waves (64 cols)
  const int rL = L >> 3;
  const int gsw = (L & 7) ^ rL;

  const int nbx = N >> 8;              // N tiles of 256
  const int cpx = gridDim.x >> 3;
  const int id = blockIdx.x;
  const int swz = (id & 7) * cpx + (id >> 3);
  const int tileN = (swz % nbx) << 8;
  const int tileM = (swz / nbx) << 7;  // M tiles of 128
  const int nkt = K >> 6;

  u16* const A0 = &Abuf[0][0];
  u16* const A1 = &Abuf[1][0];
  u16* const B0 = &Bbuf[0][0];
  u16* const B1 = &Bbuf[1][0];

  auto stageQ = [&](const u16* Mp, int gRow, int kt, u16* dst) {
    int ktc = kt < nkt ? kt : nkt - 1;  // clamped tail: loads correct last tile
    const u16* src = Mp + (size_t)(gRow + w * 8 + rL) * K + (ktc << 6) + gsw * 8;
    gload_lds16(src, dst + w * 512);
  };

  f32x4 acc[4][4] = {};
  const int rsw = lc & 7;
  const int g0 = (quad ^ rsw) * 8;
  const int g1 = ((4 + quad) ^ rsw) * 8;
  const int aRow = (wr * 64 + lc) * 64;
  const int bRow = (wc * 64 + lc) * 64;

  // prologue: tile0 full (6) + tile1 {r0,r1,q0,q1} (4)
  stageQ(A, tileM + 0, 0, A0 + 0);
  stageQ(A, tileM + 64, 0, A0 + 4096);
  stageQ(Bt, tileN + 0, 0, B0 + 0);
  stageQ(Bt, tileN + 64, 0, B0 + 4096);
  stageQ(Bt, tileN + 128, 0, B0 + 8192);
  stageQ(Bt, tileN + 192, 0, B0 + 12288);
  stageQ(Bt, tileN + 0, 1, B1 + 0);
  stageQ(Bt, tileN + 64, 1, B1 + 4096);
  stageQ(A, tileM + 0, 1, A1 + 0);
  stageQ(A, tileM + 64, 1, A1 + 4096);
  asm volatile("s_waitcnt vmcnt(4)" ::: "memory");  // tile0 resident
  __builtin_amdgcn_s_barrier();

  auto group = [&](u16* Ab, u16* Bb, u16* OBb, int T) {
    bf16x8 alo[2][2], ahi[2][2], blo[2][2], bhi[2][2];
    // ph1: read A-lo + B-lo; stage B r2,r3(T+1) -> other-B
#pragma unroll
    for (int mi = 0; mi < 2; ++mi) {
      alo[mi][0] = *(const bf16x8*)&Ab[aRow + mi * 1024 + g0];
      alo[mi][1] = *(const bf16x8*)&Ab[aRow + mi * 1024 + g1];
    }
#pragma unroll
    for (int ni = 0; ni < 2; ++ni) {
      blo[ni][0] = *(const bf16x8*)&Bb[bRow + ni * 1024 + g0];
      blo[ni][1] = *(const bf16x8*)&Bb[bRow + ni * 1024 + g1];
    }
    stageQ(Bt, tileN + 128, T + 1, OBb + 8192);
    stageQ(Bt, tileN + 192, T + 1, OBb + 12288);
    asm volatile("" ::: "memory");
    __builtin_amdgcn_s_barrier();
    asm volatile("s_waitcnt lgkmcnt(0)" ::: "memory");
    __builtin_amdgcn_s_setprio(1);
#pragma unroll
    for (int mi = 0; mi < 2; ++mi)
#pragma unroll
      for (int ni = 0; ni < 2; ++ni) {
        acc[mi][ni] = __builtin_amdgcn_mfma_f32_16x16x32_bf16(alo[mi][0], blo[ni][0], acc[mi][ni], 0, 0, 0);
        acc[mi][ni] = __builtin_amdgcn_mfma_f32_16x16x32_bf16(alo[mi][1], blo[ni][1], acc[mi][ni], 0, 0, 0);
      }
    __builtin_amdgcn_s_setprio(0);
    asm volatile("" ::: "memory");
    __builtin_amdgcn_s_barrier();
    // ph2: read B-hi; no stage
#pragma unroll
    for (int ni = 0; ni < 2; ++ni) {
      bhi[ni][0] = *(const bf16x8*)&Bb[bRow + (2 + ni) * 1024 + g0];
      bhi[ni][1] = *(const bf16x8*)&Bb[bRow + (2 + ni) * 1024 + g1];
    }
    asm volatile("" ::: "memory");
    __builtin_amdgcn_s_barrier();
    asm volatile("s_waitcnt lgkmcnt(0)" ::: "memory");
    __builtin_amdgcn_s_setprio(1);
#pragma unroll
    for (int mi = 0; mi < 2; ++mi)
#pragma unroll
      for (int ni = 0; ni < 2; ++ni) {
        acc[mi][ni + 2] = __builtin_amdgcn_mfma_f32_16x16x32_bf16(alo[mi][0], bhi[ni][0], acc[mi][ni + 2], 0, 0, 0);
        acc[mi][ni + 2] = __builtin_amdgcn_mfma_f32_16x16x32_bf16(alo[mi][1], bhi[ni][1], acc[mi][ni + 2], 0, 0, 0);
      }
    __builtin_amdgcn_s_setprio(0);
    asm volatile("" ::: "memory");
    __builtin_amdgcn_s_barrier();
    // ph3: read A-hi; stage B r0,r1(T+2) -> self-B (freed by ph2-end barrier)
#pragma unroll
    for (int mi = 0; mi < 2; ++mi) {
      ahi[mi][0] = *(const bf16x8*)&Ab[aRow + (2 + mi) * 1024 + g0];
      ahi[mi][1] = *(const bf16x8*)&Ab[aRow + (2 + mi) * 1024 + g1];
    }
    stageQ(Bt, tileN + 0, T + 2, Bb + 0);
    stageQ(Bt, tileN + 64, T + 2, Bb + 4096);
    asm volatile("" ::: "memory");
    __builtin_amdgcn_s_barrier();
    asm volatile("s_waitcnt lgkmcnt(0)" ::: "memory");
    __builtin_amdgcn_s_setprio(1);
#pragma unroll
    for (int mi = 0; mi < 2; ++mi)
#pragma unroll
      for (int ni = 0; ni < 2; ++ni) {
        acc[mi + 2][ni + 2] = __builtin_amdgcn_mfma_f32_16x16x32_bf16(ahi[mi][0], bhi[ni][0], acc[mi + 2][ni + 2], 0, 0, 0);
        acc[mi + 2][ni + 2] = __builtin_amdgcn_mfma_f32_16x16x32_bf16(ahi[mi][1], bhi[ni][1], acc[mi + 2][ni + 2], 0, 0, 0);
      }
    __builtin_amdgcn_s_setprio(0);
    asm volatile("" ::: "memory");
    __builtin_amdgcn_s_barrier();
    // ph4: stage A q0,q1(T+2) -> self-A (freed by ph3-end barrier); counted vmcnt
    stageQ(A, tileM + 0, T + 2, Ab + 0);
    stageQ(A, tileM + 64, T + 2, Ab + 4096);
    asm volatile("" ::: "memory");
    __builtin_amdgcn_s_barrier();
    __builtin_amdgcn_s_setprio(1);
#pragma unroll
    for (int mi = 0; mi < 2; ++mi)
#pragma unroll
      for (int ni = 0; ni < 2; ++ni) {
        acc[mi + 2][ni] = __builtin_amdgcn_mfma_f32_16x16x32_bf16(ahi[mi][0], blo[ni][0], acc[mi + 2][ni], 0, 0, 0);
        acc[mi + 2][ni] = __builtin_amdgcn_mfma_f32_16x16x32_bf16(ahi[mi][1], blo[ni][1], acc[mi + 2][ni], 0, 0, 0);
      }
    __builtin_amdgcn_s_setprio(0);
    asm volatile("s_waitcnt vmcnt(4)" ::: "memory");  // next K-tile resident
    __builtin_amdgcn_s_barrier();
  };

  for (int T = 0; T < nkt; T += 2) {
    group(A0, B0, B1, T);
    group(A1, B1, B0, T + 1);
  }

  // drain in-flight LDS-DMA before this block's LDS can be reassigned
  asm volatile("s_waitcnt vmcnt(0)" ::: "memory");

#pragma unroll
  for (int mi = 0; mi < 4; ++mi) {
    int rowb = tileM + wr * 64 + mi * 16 + quad * 4;
#pragma unroll
    for (int ni = 0; ni < 4; ++ni) {
      int col = tileN + wc * 64 + ni * 16 + lc;
      float bv = bias[col];
#pragma unroll
      for (int r = 0; r < 4; ++r) {
        float v = acc[mi][ni][r] + bv;
        if (OUT_BF16)
          ((u16*)Cout)[(size_t)(rowb + r) * N + col] = f32_to_bf16(v);
        else
          ((float*)Cout)[(size_t)(rowb + r) * N + col] = v;
      }
    }
  }
}

// ---------------- causal flash attention, 8-wave 32x32 in-register softmax ----
// (unchanged this round)
__global__ __launch_bounds__(512, 4) void attn(const u16* __restrict__ qkvb,
                                               const u16* __restrict__ vt,
                                               u16* __restrict__ yb) {
  __shared__ __align__(16) u16 kv[2][16][512];  // [buf][0-7:K(t2*4+ds) 8-15:V(d2*4+ks)][lane*8]
  const int tid = threadIdx.x;
  const int w = tid >> 6, L = tid & 63;
  const int l5 = L & 31, hi = L >> 5;
  const int bh = blockIdx.x;
  const int b = bh >> 4, h = bh & 15;
  const int qt = (blockIdx.y < 4) ? (7 - blockIdx.y) : (blockIdx.y - 4);
  const float e_c = 0.18033688f;          // (1/sqrt(64)) * log2(e)
  const int qbase = qt * 256;
  const int wq = qbase + w * 32;          // wave's first q row
  const int nk = qbase + 256;             // kb upper bound (exclusive)

  const int u = w - 4;
  const u16* kb0 = qkvb + (size_t)(b * 2048 + (w >> 1) * 32 + l5) * 3072 + 1024 +
                   h * 64 + (w & 1) * 32 + hi * 8;
  const u16* vb0 = vt + (size_t)(bh * 64 + (u >> 1) * 32 + l5) * 2048 +
                   (u & 1) * 32 + hi * 8;

  auto stage = [&](int kb2, int buf) {
    if (w < 4) {
      const u16* s = kb0 + (size_t)kb2 * 3072;
      gload_lds16(s, &kv[buf][2 * w][0]);
      gload_lds16(s + 16, &kv[buf][2 * w + 1][0]);
    } else {
      const u16* s = vb0 + kb2;
      gload_lds16(s, &kv[buf][8 + 2 * u][0]);
      gload_lds16(s + 16, &kv[buf][8 + 2 * u + 1][0]);
    }
  };

  const int qrow = wq + l5;               // this lane's q row (one column of S^T)
  bf16x8 qf[4];
  {
    const u16* qp = qkvb + ((size_t)(b * 2048 + qrow) * 3072 + h * 64 + hi * 8);
#pragma unroll
    for (int ds = 0; ds < 4; ++ds) qf[ds] = *(const bf16x8*)(qp + ds * 16);
  }
  f32x16 o0 = {}, o1 = {};
  float lsum = 0.f;

  int par = 0;
  stage(0, 0);  // prologue: tile0 in flight

  for (int kb = 0; kb < nk; kb += 64) {
    __syncthreads();  // drains DMA issued a full tile ago; kv[par] resident
    stage((kb + 64 < nk) ? kb + 64 : 0, par ^ 1);  // depth-1 prefetch (clamped)

    if (kb <= wq + 31) {  // wave-uniform: this wave has unmasked rows in tile
      const bool part = (kb + 63 > wq);   // some rows need the causal mask
      const int lim = qrow - 4 * hi - kb; // keep: (r&3)+8*(r>>2)+32*t2 <= lim

      // S^T: rows kb..kb+31 -> st0, kb+32..kb+63 -> st1
      f32x16 st0 = {}, st1 = {};
      __builtin_amdgcn_s_setprio(1);
#pragma unroll
      for (int ds = 0; ds < 4; ++ds) {
        bf16x8 k0 = *(const bf16x8*)&kv[par][ds][L * 8];
        bf16x8 k1 = *(const bf16x8*)&kv[par][4 + ds][L * 8];
        st0 = __builtin_amdgcn_mfma_f32_32x32x16_bf16(k0, qf[ds], st0, 0, 0, 0);
        st1 = __builtin_amdgcn_mfma_f32_32x32x16_bf16(k1, qf[ds], st1, 0, 0, 0);
      }
      __builtin_amdgcn_s_setprio(0);

      // softmax: p = exp2(s * e_c); mask partial tiles; per-lane lsum
#pragma unroll
      for (int r = 0; r < 16; ++r) {
        float p0 = __builtin_amdgcn_exp2f(st0[r] * e_c);
        float p1 = __builtin_amdgcn_exp2f(st1[r] * e_c);
        if (part) {
          const int br = (r & 3) + 8 * (r >> 2);
          p0 = (br <= lim) ? p0 : 0.f;
          p1 = (32 + br <= lim) ? p1 : 0.f;
        }
        st0[r] = p0;
        st1[r] = p1;
        lsum += p0 + p1;
      }

      // O^T += V^T · P  (k-permuted slices; pf words = regs in order)
      __builtin_amdgcn_s_setprio(1);
#pragma unroll
      for (int sg = 0; sg < 2; ++sg) {
        union { uint32_t u[4]; bf16x8 v; } pf0, pf1;
#pragma unroll
        for (int q2 = 0; q2 < 4; ++q2) {
          pf0.u[q2] = pack_bf16x2(st0[sg * 8 + q2 * 2], st0[sg * 8 + q2 * 2 + 1]);
          pf1.u[q2] = pack_bf16x2(st1[sg * 8 + q2 * 2], st1[sg * 8 + q2 * 2 + 1]);
        }
        const int ks0 = sg, ks1 = 2 + sg;  // slices of t2=0 / t2=1
        bf16x8 va = *(const bf16x8*)&kv[par][8 + ks0][L * 8];    // d2=0
        bf16x8 vb = *(const bf16x8*)&kv[par][12 + ks0][L * 8];   // d2=1
        o0 = __builtin_amdgcn_mfma_f32_32x32x16_bf16(va, pf0.v, o0, 0, 0, 0);
        o1 = __builtin_amdgcn_mfma_f32_32x32x16_bf16(vb, pf0.v, o1, 0, 0, 0);
        va = *(const bf16x8*)&kv[par][8 + ks1][L * 8];
        vb = *(const bf16x8*)&kv[par][12 + ks1][L * 8];
        o0 = __builtin_amdgcn_mfma_f32_32x32x16_bf16(va, pf1.v, o0, 0, 0, 0);
        o1 = __builtin_amdgcn_mfma_f32_32x32x16_bf16(vb, pf1.v, o1, 0, 0, 0);
      }
      __builtin_amdgcn_s_setprio(0);
    }

    par ^= 1;
  }

  // column sum: this lane has half the rows of column q; partner (hi^1) the rest
  lsum += __shfl_xor(lsum, 32);
  float inv = 1.f / lsum;

  // store y[qrow][h*64 + d]; lane's d = 32*d2 + 8*g + 4*hi + (0..3)
  u16* yp = yb + (size_t)(b * 2048 + qrow) * 1024 + h * 64 + hi * 4;
#pragma unroll
  for (int g = 0; g < 4; ++g) {
    uint2 pk;
    pk.x = pack_bf16x2(o0[g * 4 + 0] * inv, o0[g * 4 + 1] * inv);
    pk.y = pack_bf16x2(o0[g * 4 + 2] * inv, o0[g * 4 + 3] * inv);
    *(uint2*)(yp + g * 8) = pk;
    pk.x = pack_bf16x2(o1[g * 4 + 0] * inv, o1[g * 4 + 1] * inv);
    pk.y = pack_bf16x2(o1[g * 4 + 2] * inv, o1[g * 4 + 3] * inv);
    *(uint2*)(yp + 32 + g * 8) = pk;
  }

  // drain the final dummy prefetch before this block's LDS can be reassigned
  asm volatile("s_waitcnt vmcnt(0)" ::: "memory");
}

extern "C" void kernel_launch(void* const* d_in, const int* in_sizes, int n_in,
                              void* d_out, int out_size, void* d_ws, size_t ws_size,
                              hipStream_t stream) {
  const float* x = (const float*)d_in[0];
  const float* w_attn = (const float*)d_in[1];
  const float* b_attn = (const float*)d_in[2];
  const float* w_proj = (const float*)d_in[3];
  const float* b_proj = (const float*)d_in[4];
  float* out = (float*)d_out;

  char* ws = (char*)d_ws;
  u16* xb = (u16*)ws;    ws += (size_t)8192 * 1024 * 2;
  u16* waT = (u16*)ws;   ws += (size_t)3072 * 1024 * 2;
  u16* wpT = (u16*)ws;   ws += (size_t)1024 * 1024 * 2;
  u16* qkvb = (u16*)ws;  ws += (size_t)8192 * 3072 * 2;
  u16* vtb = (u16*)ws;   ws += (size_t)64 * 64 * 2048 * 2;
  u16* yb = (u16*)ws;    ws += (size_t)8192 * 1024 * 2;

  cvt_bf16<<<8192, 256, 0, stream>>>(x, xb, 8192 * 1024);
  tconv<<<dim3(3072 / 64, 1024 / 64), 256, 0, stream>>>(w_attn, waT, 1024, 3072);
  tconv<<<dim3(1024 / 64, 1024 / 64), 256, 0, stream>>>(w_proj, wpT, 1024, 1024);
  // QKV: 256^2 tiles, grid = 32*12 = 384 blocks
  gemm256<1><<<dim3(384), 512, 0, stream>>>(xb, waT, b_attn, qkvb, 8192, 3072, 1024);
  vtrans<<<dim3(64, 32), 256, 0, stream>>>(qkvb, vtb);
  attn<<<dim3(64, 8), 512, 0, stream>>>(qkvb, vtb, yb);
  // proj: 128x256 tiles, grid = 64*4 = 256 blocks = exactly 1 full round
  gemm128<0><<<dim3(256), 512, 0, stream>>>(yb, wpT, b_proj, out, 8192, 1024, 1024);
}

// Round 9
// 240.935 us; speedup vs baseline: 1.1636x; 1.0229x over previous
//
#include <hip/hip_runtime.h>
#include <cstdint>
#include <cstddef>

typedef unsigned short u16;
typedef __bf16 bf16_t;
typedef bf16_t bf16x8 __attribute__((ext_vector_type(8)));
typedef float f32x4 __attribute__((ext_vector_type(4)));
typedef float f32x16 __attribute__((ext_vector_type(16)));

__device__ __forceinline__ u16 f32_to_bf16(float f) {
  uint32_t u = __builtin_bit_cast(uint32_t, f);
  u += 0x7fffu + ((u >> 16) & 1u);   // RNE
  return (u16)(u >> 16);
}

// pack two f32 -> two bf16 in one u32 (round-half-up + v_perm_b32); low word = lo
__device__ __forceinline__ uint32_t pack_bf16x2(float lo, float hi) {
  uint32_t a = __builtin_bit_cast(uint32_t, hi) + 0x8000u;
  uint32_t b = __builtin_bit_cast(uint32_t, lo) + 0x8000u;
  return __builtin_amdgcn_perm(a, b, 0x07060302u);
}

// async global->LDS, 16B per lane. LDS dest is wave-uniform base; HW adds lane*16.
__device__ __forceinline__ void gload_lds16(const void* g, void* l) {
  __builtin_amdgcn_global_load_lds(
      (const __attribute__((address_space(1))) unsigned int*)g,
      (__attribute__((address_space(3))) unsigned int*)l, 16, 0, 0);
}

// ---------------- fp32 -> bf16 elementwise convert ----------------
__global__ void cvt_bf16(const float* __restrict__ in, u16* __restrict__ out, int n) {
  int i = (blockIdx.x * 256 + threadIdx.x) * 4;
  if (i < n) {
    float4 f = *(const float4*)(in + i);
    ushort4 o;
    o.x = f32_to_bf16(f.x); o.y = f32_to_bf16(f.y);
    o.z = f32_to_bf16(f.z); o.w = f32_to_bf16(f.w);
    *(ushort4*)(out + i) = o;
  }
}

// ---------------- fp32 [R][C] -> bf16 [C][R] transpose-convert ----------------
__global__ void tconv(const float* __restrict__ in, u16* __restrict__ out, int R, int C) {
  __shared__ u16 t[64][80];
  int tid = threadIdx.x;
  int cb = blockIdx.x * 64, rb = blockIdx.y * 64;
  int rr = tid >> 2, cg = (tid & 3) * 16;
  const float* ip = in + (size_t)(rb + rr) * C + cb + cg;
#pragma unroll
  for (int i = 0; i < 16; ++i) t[rr][cg + i] = f32_to_bf16(ip[i]);
  __syncthreads();
  int cc = tid >> 2, rg = (tid & 3) * 16;
  u16* op = out + (size_t)(cb + cc) * R + rb + rg;
  union { uint4 v[2]; u16 s[16]; } tmp;
#pragma unroll
  for (int i = 0; i < 16; ++i) tmp.s[i] = t[rg + i][cc];
  *(uint4*)op = tmp.v[0];
  *(uint4*)(op + 8) = tmp.v[1];
}

// ---------------- 256x256 8-phase bf16 GEMM, QKV variant ----------------
// C[M,N] = A[M,K]*Bt[N,K]^T + bias. Blocks with tileN < 2048 (Q,K cols) store
// bf16 row-major into qkvb. Blocks with tileN >= 2048 (V cols) store DIRECTLY
// into Vt' [bh][d=64][t=2048] transposed, with the t-permutation
// {0-3,8-11,4-7,12-15} per 16-group (= swap bits 2-3 of t = swap quad bits),
// replacing the former vtrans kernel. r=0..3 stays 4 consecutive storage
// slots -> one aligned 8B ushort4 store per (mi,ni); the 4 quads of a wave
// cover 32 contiguous t-bytes per column, so L2 assembles full lines.
// V slice of qkvb is never written (and never read). Numerics bit-identical
// to gemm-then-vtrans (same f32_to_bf16 RNE, vtrans was a pass-through).
__global__ __launch_bounds__(512, 2) void gemm_qkv(const u16* __restrict__ A,
                                                   const u16* __restrict__ Bt,
                                                   const float* __restrict__ bias,
                                                   u16* __restrict__ qkvb,
                                                   u16* __restrict__ vtb,
                                                   int M, int N, int K) {
  __shared__ __align__(16) u16 lds[2][2][16384];  // [buf][0=A,1=B][256*64]
  const int tid = threadIdx.x;
  const int w = tid >> 6, L = tid & 63;
  const int quad = L >> 4, lc = L & 15;
  const int wr = w >> 2, wc = w & 3;          // 2 M-waves x 4 N-waves
  const int wrM = wr * 128, wcN = wc * 64;
  const int rL = L >> 3;                       // row within a wave's 8-row chunk
  const int gsw = (L & 7) ^ rL;                // pre-swizzled source granule

  // XCD-aware bijective block swizzle (gridDim.x % 8 == 0)
  const int nbx = N >> 8;
  const int cpx = gridDim.x >> 3;
  const int id = blockIdx.x;
  const int swz = (id & 7) * cpx + (id >> 3);
  const int tileN = (swz % nbx) << 8;
  const int tileM = (swz / nbx) << 8;
  const int nkt = K >> 6;

  u16* const A0 = &lds[0][0][0];
  u16* const B0 = &lds[0][1][0];
  u16* const A1 = &lds[1][0][0];
  u16* const B1 = &lds[1][1][0];

  // stage one 64-row quarter (8 rows per wave, 16B per lane, linear LDS dest)
  auto stageQ = [&](const u16* Mp, int gRow, int kt, u16* reg) {
    int ktc = kt < nkt ? kt : nkt - 1;  // clamped tail: region-safe, count-safe
    const u16* src = Mp + (size_t)(gRow + w * 8 + rL) * K + (ktc << 6) + gsw * 8;
    gload_lds16(src, reg + w * 512);
  };

  f32x4 acc[8][4] = {};
  const int rsw = lc & 7;
  const int g0 = (quad ^ rsw) * 8;        // swizzled ds_read granule, ks=0
  const int g1 = ((4 + quad) ^ rsw) * 8;  // ks=1
  const int aRow = (wrM + lc) * 64;
  const int bRow = (wcN + lc) * 64;

  // ---- prologue: tile0 (8 quarters) + tile1 (6 quarters; B-hi comes at ph1)
  stageQ(A, tileM + 0, 0, A0 + 0);
  stageQ(A, tileM + 128, 0, A0 + 8192);
  stageQ(Bt, tileN + 0, 0, B0 + 0);
  stageQ(Bt, tileN + 64, 0, B0 + 4096);
  stageQ(A, tileM + 64, 0, A0 + 4096);
  stageQ(A, tileM + 192, 0, A0 + 12288);
  stageQ(Bt, tileN + 128, 0, B0 + 8192);
  stageQ(Bt, tileN + 192, 0, B0 + 12288);
  stageQ(A, tileM + 0, 1, A1 + 0);
  stageQ(A, tileM + 128, 1, A1 + 8192);
  stageQ(Bt, tileN + 0, 1, B1 + 0);
  stageQ(Bt, tileN + 64, 1, B1 + 4096);
  stageQ(A, tileM + 64, 1, A1 + 4096);
  stageQ(A, tileM + 192, 1, A1 + 12288);
  asm volatile("s_waitcnt vmcnt(6)" ::: "memory");  // tile0 resident
  __builtin_amdgcn_s_barrier();

  // ---- one 4-phase group: compute K-tile T from (Ab,Bb); prefetch
  //      B-hi(T+1)->Bob at ph1, tile(T+2)->(Ab,Bb) at ph2/3/4.
  auto group = [&](u16* Ab, u16* Bb, u16* Bob, int T) {
    bf16x8 af[4][2], blo[2][2], bhi[2][2];
    // ph1: read A-lo + B-lo; stage B r2,r3 of T+1 (other buf)
#pragma unroll
    for (int mi = 0; mi < 4; ++mi) {
      af[mi][0] = *(const bf16x8*)&Ab[aRow + mi * 1024 + g0];
      af[mi][1] = *(const bf16x8*)&Ab[aRow + mi * 1024 + g1];
    }
#pragma unroll
    for (int ni = 0; ni < 2; ++ni) {
      blo[ni][0] = *(const bf16x8*)&Bb[bRow + ni * 1024 + g0];
      blo[ni][1] = *(const bf16x8*)&Bb[bRow + ni * 1024 + g1];
    }
    stageQ(Bt, tileN + 128, T + 1, Bob + 8192);
    stageQ(Bt, tileN + 192, T + 1, Bob + 12288);
    asm volatile("" ::: "memory");
    __builtin_amdgcn_s_barrier();
    asm volatile("s_waitcnt lgkmcnt(0)" ::: "memory");
    __builtin_amdgcn_s_setprio(1);
#pragma unroll
    for (int mi = 0; mi < 4; ++mi)
#pragma unroll
      for (int ni = 0; ni < 2; ++ni) {
        acc[mi][ni] = __builtin_amdgcn_mfma_f32_16x16x32_bf16(af[mi][0], blo[ni][0], acc[mi][ni], 0, 0, 0);
        acc[mi][ni] = __builtin_amdgcn_mfma_f32_16x16x32_bf16(af[mi][1], blo[ni][1], acc[mi][ni], 0, 0, 0);
      }
    __builtin_amdgcn_s_setprio(0);
    asm volatile("" ::: "memory");
    __builtin_amdgcn_s_barrier();
    // ph2: read B-hi; stage A q0,q2 of T+2 (freed by ph1 reads)
#pragma unroll
    for (int ni = 0; ni < 2; ++ni) {
      bhi[ni][0] = *(const bf16x8*)&Bb[bRow + (2 + ni) * 1024 + g0];
      bhi[ni][1] = *(const bf16x8*)&Bb[bRow + (2 + ni) * 1024 + g1];
    }
    stageQ(A, tileM + 0, T + 2, Ab + 0);
    stageQ(A, tileM + 128, T + 2, Ab + 8192);
    asm volatile("" ::: "memory");
    __builtin_amdgcn_s_barrier();
    asm volatile("s_waitcnt lgkmcnt(0)" ::: "memory");
    __builtin_amdgcn_s_setprio(1);
#pragma unroll
    for (int mi = 0; mi < 4; ++mi)
#pragma unroll
      for (int ni = 0; ni < 2; ++ni) {
        acc[mi][ni + 2] = __builtin_amdgcn_mfma_f32_16x16x32_bf16(af[mi][0], bhi[ni][0], acc[mi][ni + 2], 0, 0, 0);
        acc[mi][ni + 2] = __builtin_amdgcn_mfma_f32_16x16x32_bf16(af[mi][1], bhi[ni][1], acc[mi][ni + 2], 0, 0, 0);
      }
    __builtin_amdgcn_s_setprio(0);
    asm volatile("" ::: "memory");
    __builtin_amdgcn_s_barrier();
    // ph3: read A-hi; stage B r0,r1 of T+2 (freed by ph2 reads)
#pragma unroll
    for (int mi = 0; mi < 4; ++mi) {
      af[mi][0] = *(const bf16x8*)&Ab[aRow + (4 + mi) * 1024 + g0];
      af[mi][1] = *(const bf16x8*)&Ab[aRow + (4 + mi) * 1024 + g1];
    }
    stageQ(Bt, tileN + 0, T + 2, Bb + 0);
    stageQ(Bt, tileN + 64, T + 2, Bb + 4096);
    asm volatile("" ::: "memory");
    __builtin_amdgcn_s_barrier();
    asm volatile("s_waitcnt lgkmcnt(0)" ::: "memory");
    __builtin_amdgcn_s_setprio(1);
#pragma unroll
    for (int mi = 0; mi < 4; ++mi)
#pragma unroll
      for (int ni = 0; ni < 2; ++ni) {
        acc[mi + 4][ni + 2] = __builtin_amdgcn_mfma_f32_16x16x32_bf16(af[mi][0], bhi[ni][0], acc[mi + 4][ni + 2], 0, 0, 0);
        acc[mi + 4][ni + 2] = __builtin_amdgcn_mfma_f32_16x16x32_bf16(af[mi][1], bhi[ni][1], acc[mi + 4][ni + 2], 0, 0, 0);
      }
    __builtin_amdgcn_s_setprio(0);
    asm volatile("" ::: "memory");
    __builtin_amdgcn_s_barrier();
    // ph4: no reads; stage A q1,q3 of T+2 (freed by ph3 reads); counted vmcnt
    stageQ(A, tileM + 64, T + 2, Ab + 4096);
    stageQ(A, tileM + 192, T + 2, Ab + 12288);
    asm volatile("" ::: "memory");
    __builtin_amdgcn_s_barrier();
    __builtin_amdgcn_s_setprio(1);
#pragma unroll
    for (int mi = 0; mi < 4; ++mi)
#pragma unroll
      for (int ni = 0; ni < 2; ++ni) {
        acc[mi + 4][ni] = __builtin_amdgcn_mfma_f32_16x16x32_bf16(af[mi][0], blo[ni][0], acc[mi + 4][ni], 0, 0, 0);
        acc[mi + 4][ni] = __builtin_amdgcn_mfma_f32_16x16x32_bf16(af[mi][1], blo[ni][1], acc[mi + 4][ni], 0, 0, 0);
      }
    __builtin_amdgcn_s_setprio(0);
    asm volatile("s_waitcnt vmcnt(6)" ::: "memory");  // next K-tile resident
    __builtin_amdgcn_s_barrier();
  };

  for (int T = 0; T < nkt; T += 2) {
    group(A0, B0, B1, T);
    group(A1, B1, B0, T + 1);
  }

  // drain in-flight LDS-DMA before this block's LDS can be reassigned
  asm volatile("s_waitcnt vmcnt(0)" ::: "memory");

  if (tileN < 2048) {
    // Q/K columns: normal bf16 row-major store into qkvb
#pragma unroll
    for (int mi = 0; mi < 8; ++mi) {
      int rowb = tileM + wrM + mi * 16 + quad * 4;
#pragma unroll
      for (int ni = 0; ni < 4; ++ni) {
        int col = tileN + wcN + ni * 16 + lc;
        float bv = bias[col];
#pragma unroll
        for (int r = 0; r < 4; ++r)
          qkvb[(size_t)(rowb + r) * N + col] = f32_to_bf16(acc[mi][ni][r] + bv);
      }
    }
  } else {
    // V columns: store transposed+permuted into vtb only (qkvb V slice unused)
#pragma unroll
    for (int mi = 0; mi < 8; ++mi) {
      int row = tileM + wrM + mi * 16 + quad * 4;
      int bq = row >> 11;
      int ts = (row & 2047 & ~12) | ((row & 4) << 1) | ((row & 8) >> 1);
#pragma unroll
      for (int ni = 0; ni < 4; ++ni) {
        int col = tileN + wcN + ni * 16 + lc;
        int cv = col - 2048;
        float bv = bias[col];
        u16* vp = vtb + (size_t)((bq * 16 + (cv >> 6)) * 64 + (cv & 63)) * 2048 + ts;
        ushort4 o;
        o.x = f32_to_bf16(acc[mi][ni][0] + bv);
        o.y = f32_to_bf16(acc[mi][ni][1] + bv);
        o.z = f32_to_bf16(acc[mi][ni][2] + bv);
        o.w = f32_to_bf16(acc[mi][ni][3] + bv);
        *(ushort4*)vp = o;
      }
    }
  }
}

// ---------------- 128x256 8-phase bf16 GEMM (exact-grid variant, proj) ---------
// Same schedule family, re-derived for BM=128: 8 waves as 2M x 4N, per-wave
// output 64x64 (acc[4][4]); LDS 96 KB. vmcnt ledger: 6 stages/group, vmcnt(4)
// once per group; B freed after ph2-end barrier, A after ph3-end.
template <int OUT_BF16>
__global__ __launch_bounds__(512, 2) void gemm128(const u16* __restrict__ A,
                                                  const u16* __restrict__ Bt,
                                                  const float* __restrict__ bias,
                                                  void* __restrict__ Cout,
                                                  int M, int N, int K) {
  __shared__ __align__(16) u16 Abuf[2][8192];    // [buf][128 rows x 64 k]
  __shared__ __align__(16) u16 Bbuf[2][16384];   // [buf][256 rows x 64 k]
  const int tid = threadIdx.x;
  const int w = tid >> 6, L = tid & 63;
  const int quad = L >> 4, lc = L & 15;
  const int wr = w >> 2, wc = w & 3;   // 2 M-waves (64 rows) x 4 N-waves (64 cols)
  const int rL = L >> 3;
  const int gsw = (L & 7) ^ rL;

  const int nbx = N >> 8;              // N tiles of 256
  const int cpx = gridDim.x >> 3;
  const int id = blockIdx.x;
  const int swz = (id & 7) * cpx + (id >> 3);
  const int tileN = (swz % nbx) << 8;
  const int tileM = (swz / nbx) << 7;  // M tiles of 128
  const int nkt = K >> 6;

  u16* const A0 = &Abuf[0][0];
  u16* const A1 = &Abuf[1][0];
  u16* const B0 = &Bbuf[0][0];
  u16* const B1 = &Bbuf[1][0];

  auto stageQ = [&](const u16* Mp, int gRow, int kt, u16* dst) {
    int ktc = kt < nkt ? kt : nkt - 1;  // clamped tail: loads correct last tile
    const u16* src = Mp + (size_t)(gRow + w * 8 + rL) * K + (ktc << 6) + gsw * 8;
    gload_lds16(src, dst + w * 512);
  };

  f32x4 acc[4][4] = {};
  const int rsw = lc & 7;
  const int g0 = (quad ^ rsw) * 8;
  const int g1 = ((4 + quad) ^ rsw) * 8;
  const int aRow = (wr * 64 + lc) * 64;
  const int bRow = (wc * 64 + lc) * 64;

  // prologue: tile0 full (6) + tile1 {r0,r1,q0,q1} (4)
  stageQ(A, tileM + 0, 0, A0 + 0);
  stageQ(A, tileM + 64, 0, A0 + 4096);
  stageQ(Bt, tileN + 0, 0, B0 + 0);
  stageQ(Bt, tileN + 64, 0, B0 + 4096);
  stageQ(Bt, tileN + 128, 0, B0 + 8192);
  stageQ(Bt, tileN + 192, 0, B0 + 12288);
  stageQ(Bt, tileN + 0, 1, B1 + 0);
  stageQ(Bt, tileN + 64, 1, B1 + 4096);
  stageQ(A, tileM + 0, 1, A1 + 0);
  stageQ(A, tileM + 64, 1, A1 + 4096);
  asm volatile("s_waitcnt vmcnt(4)" ::: "memory");  // tile0 resident
  __builtin_amdgcn_s_barrier();

  auto group = [&](u16* Ab, u16* Bb, u16* OBb, int T) {
    bf16x8 alo[2][2], ahi[2][2], blo[2][2], bhi[2][2];
    // ph1: read A-lo + B-lo; stage B r2,r3(T+1) -> other-B
#pragma unroll
    for (int mi = 0; mi < 2; ++mi) {
      alo[mi][0] = *(const bf16x8*)&Ab[aRow + mi * 1024 + g0];
      alo[mi][1] = *(const bf16x8*)&Ab[aRow + mi * 1024 + g1];
    }
#pragma unroll
    for (int ni = 0; ni < 2; ++ni) {
      blo[ni][0] = *(const bf16x8*)&Bb[bRow + ni * 1024 + g0];
      blo[ni][1] = *(const bf16x8*)&Bb[bRow + ni * 1024 + g1];
    }
    stageQ(Bt, tileN + 128, T + 1, OBb + 8192);
    stageQ(Bt, tileN + 192, T + 1, OBb + 12288);
    asm volatile("" ::: "memory");
    __builtin_amdgcn_s_barrier();
    asm volatile("s_waitcnt lgkmcnt(0)" ::: "memory");
    __builtin_amdgcn_s_setprio(1);
#pragma unroll
    for (int mi = 0; mi < 2; ++mi)
#pragma unroll
      for (int ni = 0; ni < 2; ++ni) {
        acc[mi][ni] = __builtin_amdgcn_mfma_f32_16x16x32_bf16(alo[mi][0], blo[ni][0], acc[mi][ni], 0, 0, 0);
        acc[mi][ni] = __builtin_amdgcn_mfma_f32_16x16x32_bf16(alo[mi][1], blo[ni][1], acc[mi][ni], 0, 0, 0);
      }
    __builtin_amdgcn_s_setprio(0);
    asm volatile("" ::: "memory");
    __builtin_amdgcn_s_barrier();
    // ph2: read B-hi; no stage
#pragma unroll
    for (int ni = 0; ni < 2; ++ni) {
      bhi[ni][0] = *(const bf16x8*)&Bb[bRow + (2 + ni) * 1024 + g0];
      bhi[ni][1] = *(const bf16x8*)&Bb[bRow + (2 + ni) * 1024 + g1];
    }
    asm volatile("" ::: "memory");
    __builtin_amdgcn_s_barrier();
    asm volatile("s_waitcnt lgkmcnt(0)" ::: "memory");
    __builtin_amdgcn_s_setprio(1);
#pragma unroll
    for (int mi = 0; mi < 2; ++mi)
#pragma unroll
      for (int ni = 0; ni < 2; ++ni) {
        acc[mi][ni + 2] = __builtin_amdgcn_mfma_f32_16x16x32_bf16(alo[mi][0], bhi[ni][0], acc[mi][ni + 2], 0, 0, 0);
        acc[mi][ni + 2] = __builtin_amdgcn_mfma_f32_16x16x32_bf16(alo[mi][1], bhi[ni][1], acc[mi][ni + 2], 0, 0, 0);
      }
    __builtin_amdgcn_s_setprio(0);
    asm volatile("" ::: "memory");
    __builtin_amdgcn_s_barrier();
    // ph3: read A-hi; stage B r0,r1(T+2) -> self-B (freed by ph2-end barrier)
#pragma unroll
    for (int mi = 0; mi < 2; ++mi) {
      ahi[mi][0] = *(const bf16x8*)&Ab[aRow + (2 + mi) * 1024 + g0];
      ahi[mi][1] = *(const bf16x8*)&Ab[aRow + (2 + mi) * 1024 + g1];
    }
    stageQ(Bt, tileN + 0, T + 2, Bb + 0);
    stageQ(Bt, tileN + 64, T + 2, Bb + 4096);
    asm volatile("" ::: "memory");
    __builtin_amdgcn_s_barrier();
    asm volatile("s_waitcnt lgkmcnt(0)" ::: "memory");
    __builtin_amdgcn_s_setprio(1);
#pragma unroll
    for (int mi = 0; mi < 2; ++mi)
#pragma unroll
      for (int ni = 0; ni < 2; ++ni) {
        acc[mi + 2][ni + 2] = __builtin_amdgcn_mfma_f32_16x16x32_bf16(ahi[mi][0], bhi[ni][0], acc[mi + 2][ni + 2], 0, 0, 0);
        acc[mi + 2][ni + 2] = __builtin_amdgcn_mfma_f32_16x16x32_bf16(ahi[mi][1], bhi[ni][1], acc[mi + 2][ni + 2], 0, 0, 0);
      }
    __builtin_amdgcn_s_setprio(0);
    asm volatile("" ::: "memory");
    __builtin_amdgcn_s_barrier();
    // ph4: stage A q0,q1(T+2) -> self-A (freed by ph3-end barrier); counted vmcnt
    stageQ(A, tileM + 0, T + 2, Ab + 0);
    stageQ(A, tileM + 64, T + 2, Ab + 4096);
    asm volatile("" ::: "memory");
    __builtin_amdgcn_s_barrier();
    __builtin_amdgcn_s_setprio(1);
#pragma unroll
    for (int mi = 0; mi < 2; ++mi)
#pragma unroll
      for (int ni = 0; ni < 2; ++ni) {
        acc[mi + 2][ni] = __builtin_amdgcn_mfma_f32_16x16x32_bf16(ahi[mi][0], blo[ni][0], acc[mi + 2][ni], 0, 0, 0);
        acc[mi + 2][ni] = __builtin_amdgcn_mfma_f32_16x16x32_bf16(ahi[mi][1], blo[ni][1], acc[mi + 2][ni], 0, 0, 0);
      }
    __builtin_amdgcn_s_setprio(0);
    asm volatile("s_waitcnt vmcnt(4)" ::: "memory");  // next K-tile resident
    __builtin_amdgcn_s_barrier();
  };

  for (int T = 0; T < nkt; T += 2) {
    group(A0, B0, B1, T);
    group(A1, B1, B0, T + 1);
  }

  // drain in-flight LDS-DMA before this block's LDS can be reassigned
  asm volatile("s_waitcnt vmcnt(0)" ::: "memory");

#pragma unroll
  for (int mi = 0; mi < 4; ++mi) {
    int rowb = tileM + wr * 64 + mi * 16 + quad * 4;
#pragma unroll
    for (int ni = 0; ni < 4; ++ni) {
      int col = tileN + wc * 64 + ni * 16 + lc;
      float bv = bias[col];
#pragma unroll
      for (int r = 0; r < 4; ++r) {
        float v = acc[mi][ni][r] + bv;
        if (OUT_BF16)
          ((u16*)Cout)[(size_t)(rowb + r) * N + col] = f32_to_bf16(v);
        else
          ((float*)Cout)[(size_t)(rowb + r) * N + col] = v;
      }
    }
  }
}

// ---------------- causal flash attention, 8-wave 32x32 in-register softmax ----
// (unchanged this round)
__global__ __launch_bounds__(512, 4) void attn(const u16* __restrict__ qkvb,
                                               const u16* __restrict__ vt,
                                               u16* __restrict__ yb) {
  __shared__ __align__(16) u16 kv[2][16][512];  // [buf][0-7:K(t2*4+ds) 8-15:V(d2*4+ks)][lane*8]
  const int tid = threadIdx.x;
  const int w = tid >> 6, L = tid & 63;
  const int l5 = L & 31, hi = L >> 5;
  const int bh = blockIdx.x;
  const int b = bh >> 4, h = bh & 15;
  const int qt = (blockIdx.y < 4) ? (7 - blockIdx.y) : (blockIdx.y - 4);
  const float e_c = 0.18033688f;          // (1/sqrt(64)) * log2(e)
  const int qbase = qt * 256;
  const int wq = qbase + w * 32;          // wave's first q row
  const int nk = qbase + 256;             // kb upper bound (exclusive)

  const int u = w - 4;
  const u16* kb0 = qkvb + (size_t)(b * 2048 + (w >> 1) * 32 + l5) * 3072 + 1024 +
                   h * 64 + (w & 1) * 32 + hi * 8;
  const u16* vb0 = vt + (size_t)(bh * 64 + (u >> 1) * 32 + l5) * 2048 +
                   (u & 1) * 32 + hi * 8;

  auto stage = [&](int kb2, int buf) {
    if (w < 4) {
      const u16* s = kb0 + (size_t)kb2 * 3072;
      gload_lds16(s, &kv[buf][2 * w][0]);
      gload_lds16(s + 16, &kv[buf][2 * w + 1][0]);
    } else {
      const u16* s = vb0 + kb2;
      gload_lds16(s, &kv[buf][8 + 2 * u][0]);
      gload_lds16(s + 16, &kv[buf][8 + 2 * u + 1][0]);
    }
  };

  const int qrow = wq + l5;               // this lane's q row (one column of S^T)
  bf16x8 qf[4];
  {
    const u16* qp = qkvb + ((size_t)(b * 2048 + qrow) * 3072 + h * 64 + hi * 8);
#pragma unroll
    for (int ds = 0; ds < 4; ++ds) qf[ds] = *(const bf16x8*)(qp + ds * 16);
  }
  f32x16 o0 = {}, o1 = {};
  float lsum = 0.f;

  int par = 0;
  stage(0, 0);  // prologue: tile0 in flight

  for (int kb = 0; kb < nk; kb += 64) {
    __syncthreads();  // drains DMA issued a full tile ago; kv[par] resident
    stage((kb + 64 < nk) ? kb + 64 : 0, par ^ 1);  // depth-1 prefetch (clamped)

    if (kb <= wq + 31) {  // wave-uniform: this wave has unmasked rows in tile
      const bool part = (kb + 63 > wq);   // some rows need the causal mask
      const int lim = qrow - 4 * hi - kb; // keep: (r&3)+8*(r>>2)+32*t2 <= lim

      // S^T: rows kb..kb+31 -> st0, kb+32..kb+63 -> st1
      f32x16 st0 = {}, st1 = {};
      __builtin_amdgcn_s_setprio(1);
#pragma unroll
      for (int ds = 0; ds < 4; ++ds) {
        bf16x8 k0 = *(const bf16x8*)&kv[par][ds][L * 8];
        bf16x8 k1 = *(const bf16x8*)&kv[par][4 + ds][L * 8];
        st0 = __builtin_amdgcn_mfma_f32_32x32x16_bf16(k0, qf[ds], st0, 0, 0, 0);
        st1 = __builtin_amdgcn_mfma_f32_32x32x16_bf16(k1, qf[ds], st1, 0, 0, 0);
      }
      __builtin_amdgcn_s_setprio(0);

      // softmax: p = exp2(s * e_c); mask partial tiles; per-lane lsum
#pragma unroll
      for (int r = 0; r < 16; ++r) {
        float p0 = __builtin_amdgcn_exp2f(st0[r] * e_c);
        float p1 = __builtin_amdgcn_exp2f(st1[r] * e_c);
        if (part) {
          const int br = (r & 3) + 8 * (r >> 2);
          p0 = (br <= lim) ? p0 : 0.f;
          p1 = (32 + br <= lim) ? p1 : 0.f;
        }
        st0[r] = p0;
        st1[r] = p1;
        lsum += p0 + p1;
      }

      // O^T += V^T · P  (k-permuted slices; pf words = regs in order)
      __builtin_amdgcn_s_setprio(1);
#pragma unroll
      for (int sg = 0; sg < 2; ++sg) {
        union { uint32_t u[4]; bf16x8 v; } pf0, pf1;
#pragma unroll
        for (int q2 = 0; q2 < 4; ++q2) {
          pf0.u[q2] = pack_bf16x2(st0[sg * 8 + q2 * 2], st0[sg * 8 + q2 * 2 + 1]);
          pf1.u[q2] = pack_bf16x2(st1[sg * 8 + q2 * 2], st1[sg * 8 + q2 * 2 + 1]);
        }
        const int ks0 = sg, ks1 = 2 + sg;  // slices of t2=0 / t2=1
        bf16x8 va = *(const bf16x8*)&kv[par][8 + ks0][L * 8];    // d2=0
        bf16x8 vb = *(const bf16x8*)&kv[par][12 + ks0][L * 8];   // d2=1
        o0 = __builtin_amdgcn_mfma_f32_32x32x16_bf16(va, pf0.v, o0, 0, 0, 0);
        o1 = __builtin_amdgcn_mfma_f32_32x32x16_bf16(vb, pf0.v, o1, 0, 0, 0);
        va = *(const bf16x8*)&kv[par][8 + ks1][L * 8];
        vb = *(const bf16x8*)&kv[par][12 + ks1][L * 8];
        o0 = __builtin_amdgcn_mfma_f32_32x32x16_bf16(va, pf1.v, o0, 0, 0, 0);
        o1 = __builtin_amdgcn_mfma_f32_32x32x16_bf16(vb, pf1.v, o1, 0, 0, 0);
      }
      __builtin_amdgcn_s_setprio(0);
    }

    par ^= 1;
  }

  // column sum: this lane has half the rows of column q; partner (hi^1) the rest
  lsum += __shfl_xor(lsum, 32);
  float inv = 1.f / lsum;

  // store y[qrow][h*64 + d]; lane's d = 32*d2 + 8*g + 4*hi + (0..3)
  u16* yp = yb + (size_t)(b * 2048 + qrow) * 1024 + h * 64 + hi * 4;
#pragma unroll
  for (int g = 0; g < 4; ++g) {
    uint2 pk;
    pk.x = pack_bf16x2(o0[g * 4 + 0] * inv, o0[g * 4 + 1] * inv);
    pk.y = pack_bf16x2(o0[g * 4 + 2] * inv, o0[g * 4 + 3] * inv);
    *(uint2*)(yp + g * 8) = pk;
    pk.x = pack_bf16x2(o1[g * 4 + 0] * inv, o1[g * 4 + 1] * inv);
    pk.y = pack_bf16x2(o1[g * 4 + 2] * inv, o1[g * 4 + 3] * inv);
    *(uint2*)(yp + 32 + g * 8) = pk;
  }

  // drain the final dummy prefetch before this block's LDS can be reassigned
  asm volatile("s_waitcnt vmcnt(0)" ::: "memory");
}

extern "C" void kernel_launch(void* const* d_in, const int* in_sizes, int n_in,
                              void* d_out, int out_size, void* d_ws, size_t ws_size,
                              hipStream_t stream) {
  const float* x = (const float*)d_in[0];
  const float* w_attn = (const float*)d_in[1];
  const float* b_attn = (const float*)d_in[2];
  const float* w_proj = (const float*)d_in[3];
  const float* b_proj = (const float*)d_in[4];
  float* out = (float*)d_out;

  char* ws = (char*)d_ws;
  u16* xb = (u16*)ws;    ws += (size_t)8192 * 1024 * 2;
  u16* waT = (u16*)ws;   ws += (size_t)3072 * 1024 * 2;
  u16* wpT = (u16*)ws;   ws += (size_t)1024 * 1024 * 2;
  u16* qkvb = (u16*)ws;  ws += (size_t)8192 * 3072 * 2;
  u16* vtb = (u16*)ws;   ws += (size_t)64 * 64 * 2048 * 2;
  u16* yb = (u16*)ws;    ws += (size_t)8192 * 1024 * 2;

  cvt_bf16<<<8192, 256, 0, stream>>>(x, xb, 8192 * 1024);
  tconv<<<dim3(3072 / 64, 1024 / 64), 256, 0, stream>>>(w_attn, waT, 1024, 3072);
  tconv<<<dim3(1024 / 64, 1024 / 64), 256, 0, stream>>>(w_proj, wpT, 1024, 1024);
  // QKV: 256^2 tiles, grid = 32*12 = 384 blocks; V cols write vtb directly
  gemm_qkv<<<dim3(384), 512, 0, stream>>>(xb, waT, b_attn, qkvb, vtb, 8192, 3072, 1024);
  attn<<<dim3(64, 8), 512, 0, stream>>>(qkvb, vtb, yb);
  // proj: 128x256 tiles, grid = 64*4 = 256 blocks = exactly 1 full round
  gemm128<0><<<dim3(256), 512, 0, stream>>>(yb, wpT, b_proj, out, 8192, 1024, 1024);
}